// Round 1
// baseline (1740.054 us; speedup 1.0000x reference)
//
#include <hip/hip_runtime.h>

#define NP 4225      // 65*65 spatial positions
#define PR 2145      // 65*33 rfft bins

// ---------------- small projection kernels ----------------

__global__ __launch_bounds__(256) void k_q(const float* __restrict__ Q,
                                           const float* __restrict__ Wq,
                                           const float* __restrict__ bq,
                                           float* __restrict__ qv)
{
    int wid = threadIdx.x >> 6, lane = threadIdx.x & 63;
    int j = blockIdx.x * 4 + wid;            // < 4096
    float s = 0.f;
    for (int i = lane; i < 512; i += 64) s += Q[i] * Wq[j * 512 + i];
    #pragma unroll
    for (int off = 32; off; off >>= 1) s += __shfl_down(s, off);
    if (lane == 0) qv[j] = s + bq[j];
}

// qk partial: qkp[dz][h][c] = sum over 64 d of q[h,d]*Wk[h*512+d, c]
__global__ __launch_bounds__(256) void k_qk(const float* __restrict__ q,
                                            const float* __restrict__ Wk,
                                            float* __restrict__ qkp)
{
    int c = blockIdx.x * 256 + threadIdx.x;  // 0..511
    int h = blockIdx.y;
    int dz = blockIdx.z;
    __shared__ float qs[64];
    if (threadIdx.x < 64) qs[threadIdx.x] = q[h * 512 + dz * 64 + threadIdx.x];
    __syncthreads();
    float s = 0.f;
    for (int d = 0; d < 64; d++)
        s += qs[d] * Wk[(h * 512 + dz * 64 + d) * 512 + c];
    qkp[(dz * 8 + h) * 512 + c] = s;
}

__global__ __launch_bounds__(512) void k_qb(const float* __restrict__ q,
                                            const float* __restrict__ bk,
                                            float* __restrict__ qb)
{
    int h = threadIdx.x >> 6, lane = threadIdx.x & 63;
    float s = 0.f;
    for (int d = lane; d < 512; d += 64) s += q[h * 512 + d] * bk[h * 512 + d];
    #pragma unroll
    for (int off = 32; off; off >>= 1) s += __shfl_down(s, off);
    if (lane == 0) qb[h] = s;
}

// A-logit partials: Ap[cz][h][p] = sum over 64 c of qk[h,c]*K[c,p]
__global__ __launch_bounds__(256) void k_alogits(const float* __restrict__ qkp,
                                                 const float* __restrict__ K,
                                                 float* __restrict__ Ap)
{
    int tid = threadIdx.x;
    int cz = blockIdx.y;
    __shared__ float sqk[8][64];
    for (int i = tid; i < 512; i += 256) {
        int h = i >> 6, cc = i & 63;
        float s = 0.f;
        #pragma unroll
        for (int dz = 0; dz < 8; dz++) s += qkp[(dz * 8 + h) * 512 + cz * 64 + cc];
        sqk[h][cc] = s;
    }
    __syncthreads();
    int p = blockIdx.x * 256 + tid;
    bool ok = p < NP;
    float acc[8] = {};
    for (int c = 0; c < 64; c++) {
        float kv = ok ? K[(cz * 64 + c) * NP + p] : 0.f;
        #pragma unroll
        for (int h = 0; h < 8; h++) acc[h] += sqk[h][c] * kv;
    }
    if (ok) {
        #pragma unroll
        for (int h = 0; h < 8; h++) Ap[(cz * 8 + h) * NP + p] = acc[h];
    }
}

// ---------------- filter branch kernels ----------------

// 1x1 conv = GEMM: Y[512][4225] = Wm[512][512] x X[512][4225]
__global__ __launch_bounds__(256) void k_conv1x1(const float* __restrict__ Wm,
                                                 const float* __restrict__ X,
                                                 float* __restrict__ Y)
{
    __shared__ float As[16][68];
    __shared__ float Bs[16][64];
    int tid = threadIdx.x;
    int tx = tid & 15, ty = tid >> 4;
    int bm = blockIdx.y * 64, bn = blockIdx.x * 64;
    float acc[4][4] = {};
    for (int k0 = 0; k0 < 512; k0 += 16) {
        #pragma unroll
        for (int i = 0; i < 4; i++) {
            int idx = tid + i * 256;
            int mm = idx >> 4, kk = idx & 15;
            As[kk][mm] = Wm[(bm + mm) * 512 + k0 + kk];
        }
        #pragma unroll
        for (int i = 0; i < 4; i++) {
            int idx = tid + i * 256;
            int kk = idx >> 6, nn = idx & 63;
            int n = bn + nn;
            Bs[kk][nn] = (n < NP) ? X[(k0 + kk) * NP + n] : 0.f;
        }
        __syncthreads();
        #pragma unroll
        for (int kk = 0; kk < 16; kk++) {
            float a[4], b[4];
            #pragma unroll
            for (int i = 0; i < 4; i++) a[i] = As[kk][ty * 4 + i];
            #pragma unroll
            for (int j = 0; j < 4; j++) b[j] = Bs[kk][tx * 4 + j];
            #pragma unroll
            for (int i = 0; i < 4; i++)
                #pragma unroll
                for (int j = 0; j < 4; j++) acc[i][j] += a[i] * b[j];
        }
        __syncthreads();
    }
    #pragma unroll
    for (int i = 0; i < 4; i++) {
        int m = bm + ty * 4 + i;
        #pragma unroll
        for (int j = 0; j < 4; j++) {
            int n = bn + tx * 4 + j;
            if (n < NP) Y[m * NP + n] = acc[i][j];
        }
    }
}

// 3x3 conv (pad 1) on relu(F0), plus residual F0:  Y = conv3x3(relu(F0), W2) + F0
__global__ __launch_bounds__(256) void k_conv3x3(const float* __restrict__ W2,
                                                 const float* __restrict__ F0,
                                                 float* __restrict__ Y)
{
    __shared__ float As[16][68];
    __shared__ float Bs[16][64];
    int tid = threadIdx.x;
    int tx = tid & 15, ty = tid >> 4;
    int bm = blockIdx.y * 64, bn = blockIdx.x * 64;
    float acc[4][4] = {};
    for (int tap = 0; tap < 9; tap++) {
        int ky = tap / 3 - 1, kx = tap % 3 - 1;
        for (int k0 = 0; k0 < 512; k0 += 16) {
            #pragma unroll
            for (int i = 0; i < 4; i++) {
                int idx = tid + i * 256;
                int mm = idx >> 4, kk = idx & 15;
                As[kk][mm] = W2[((bm + mm) * 512 + k0 + kk) * 9 + tap];
            }
            #pragma unroll
            for (int i = 0; i < 4; i++) {
                int idx = tid + i * 256;
                int kk = idx >> 6, nn = idx & 63;
                int p = bn + nn;
                float v = 0.f;
                if (p < NP) {
                    int py = p / 65 + ky, px = p % 65 + kx;
                    if (py >= 0 && py < 65 && px >= 0 && px < 65)
                        v = fmaxf(F0[(k0 + kk) * NP + py * 65 + px], 0.f);
                }
                Bs[kk][nn] = v;
            }
            __syncthreads();
            #pragma unroll
            for (int kk = 0; kk < 16; kk++) {
                float a[4], b[4];
                #pragma unroll
                for (int i = 0; i < 4; i++) a[i] = As[kk][ty * 4 + i];
                #pragma unroll
                for (int j = 0; j < 4; j++) b[j] = Bs[kk][tx * 4 + j];
                #pragma unroll
                for (int i = 0; i < 4; i++)
                    #pragma unroll
                    for (int j = 0; j < 4; j++) acc[i][j] += a[i] * b[j];
            }
            __syncthreads();
        }
    }
    #pragma unroll
    for (int i = 0; i < 4; i++) {
        int m = bm + ty * 4 + i;
        #pragma unroll
        for (int j = 0; j < 4; j++) {
            int n = bn + tx * 4 + j;
            if (n < NP) Y[m * NP + n] = acc[i][j] + F0[m * NP + n];
        }
    }
}

// 1x1 conv 512 -> 8 with relu on input and output: F2 = relu(W3 x relu(Y2))
__global__ __launch_bounds__(256) void k_conv8(const float* __restrict__ W3,
                                               const float* __restrict__ Y2,
                                               float* __restrict__ F2)
{
    __shared__ float w[8 * 512];
    int tid = threadIdx.x;
    for (int i = tid; i < 4096; i += 256) w[i] = W3[i];
    __syncthreads();
    int p = blockIdx.x * 256 + tid;
    if (p >= NP) return;
    float acc[8] = {};
    for (int c = 0; c < 512; c++) {
        float v = fmaxf(Y2[c * NP + p], 0.f);
        #pragma unroll
        for (int h = 0; h < 8; h++) acc[h] += w[h * 512 + c] * v;
    }
    #pragma unroll
    for (int h = 0; h < 8; h++) F2[h * NP + p] = fmaxf(acc[h], 0.f);
}

// down-proj: Fo[h][j] = sum_p F2[h][p] * Wd[j][p] + bd[j]   (one wave per j)
__global__ __launch_bounds__(256) void k_down(const float* __restrict__ F2,
                                              const float* __restrict__ Wd,
                                              const float* __restrict__ bd,
                                              float* __restrict__ Fo)
{
    int wid = threadIdx.x >> 6, lane = threadIdx.x & 63;
    int j = blockIdx.x * 4 + wid;
    if (j >= PR) return;
    const float* wr = Wd + (long)j * NP;
    float acc[8] = {};
    for (int p = lane; p < NP; p += 64) {
        float wv = wr[p];
        #pragma unroll
        for (int h = 0; h < 8; h++) acc[h] += wv * F2[h * NP + p];
    }
    #pragma unroll
    for (int h = 0; h < 8; h++) {
        #pragma unroll
        for (int off = 32; off; off >>= 1) acc[h] += __shfl_down(acc[h], off);
    }
    if (lane == 0) {
        float b = bd[j];
        #pragma unroll
        for (int h = 0; h < 8; h++) Fo[h * PR + j] = acc[h] + b;
    }
}

// ---------------- FFT / modulation / inverse (per head, DFT via twiddle table) ----------------

__global__ __launch_bounds__(1024) void k_fft(const float* __restrict__ Ap,
                                              const float* __restrict__ qb,
                                              const float* __restrict__ Fa,
                                              const float* __restrict__ Fp,
                                              float* __restrict__ A2)
{
    int h = blockIdx.x;
    int tid = threadIdx.x;
    __shared__ float As[65][65];
    __shared__ float Tr[65][33], Ti[65][33];
    __shared__ float Br[65][33], Bi[65][33];
    __shared__ double ctd[65], snd[65];
    __shared__ float ct[65], st[65];
    if (tid < 65) {
        double ang = 6.283185307179586476925286766559 * (double)tid / 65.0;
        double cv = cos(ang), sv = sin(ang);
        ctd[tid] = cv; snd[tid] = sv;
        ct[tid] = (float)cv; st[tid] = (float)sv;
    }
    const float sc = 0.04419417382415922f;   // 1/sqrt(512)
    float qbh = qb[h];
    for (int i = tid; i < NP; i += 1024) {
        float s = 0.f;
        #pragma unroll
        for (int cz = 0; cz < 8; cz++) s += Ap[(cz * 8 + h) * NP + i];
        As[i / 65][i % 65] = (s + qbh) * sc;
    }
    __syncthreads();
    // phase 1: T[y][v] = sum_x A[y][x] e^{-2pi i v x / 65}   (f64 accum)
    for (int o = tid; o < PR; o += 1024) {
        int y = o / 33, v = o % 33;
        double sr = 0.0, si = 0.0;
        for (int x = 0; x < 65; x++) {
            int m = (v * x) % 65;
            double a = (double)As[y][x];
            sr += a * ctd[m];
            si -= a * snd[m];
        }
        Tr[y][v] = (float)sr; Ti[y][v] = (float)si;
    }
    __syncthreads();
    // phase 2: Af[u][v] = sum_y e^{-2pi i u y/65} T[y][v], then amp/phase modulation
    for (int o = tid; o < PR; o += 1024) {
        int u = o / 33, v = o % 33;
        double sr = 0.0, si = 0.0;
        for (int y = 0; y < 65; y++) {
            int m = (u * y) % 65;
            double c = ctd[m], s = snd[m];
            double tr = (double)Tr[y][v], ti = (double)Ti[y][v];
            sr += tr * c + ti * s;
            si += ti * c - tr * s;
        }
        float re = (float)sr, im = (float)si;
        float mag = sqrtf(re * re + im * im);
        float ang = atan2f(im, re);
        float amp = Fa[h * PR + o] * mag;
        float ph  = Fp[h * PR + o] * ang;
        float sn, cn;
        sincosf(ph, &sn, &cn);
        Br[u][v] = amp * cn;
        Bi[u][v] = amp * sn;
    }
    __syncthreads();
    // phase 3: B[y][v] = sum_u e^{+2pi i u y/65} Af'[u][v]
    for (int o = tid; o < PR; o += 1024) {
        int y = o / 33, v = o % 33;
        float sr = 0.f, si = 0.f;
        for (int u = 0; u < 65; u++) {
            int m = (u * y) % 65;
            float c = ct[m], s = st[m];
            float ar = Br[u][v], ai = Bi[u][v];
            sr += ar * c - ai * s;
            si += ai * c + ar * s;
        }
        Tr[y][v] = sr; Ti[y][v] = si;
    }
    __syncthreads();
    // phase 4: irfft last axis (Im of bin 0 dropped, bins 1..32 doubled), 1/(65*65)
    for (int o = tid; o < NP; o += 1024) {
        int y = o / 65, x = o % 65;
        float s = Tr[y][0];
        for (int v = 1; v < 33; v++) {
            int m = (v * x) % 65;
            s += 2.f * (Tr[y][v] * ct[m] - Ti[y][v] * st[m]);
        }
        A2[h * NP + o] = s * (1.f / 4225.f);
    }
}

__global__ __launch_bounds__(1024) void k_softmax(const float* __restrict__ A2,
                                                  float* __restrict__ Wsm)
{
    int h = blockIdx.x, tid = threadIdx.x;
    __shared__ float red[1024];
    float mx = -3.0e38f;
    for (int i = tid; i < NP; i += 1024) mx = fmaxf(mx, A2[h * NP + i]);
    red[tid] = mx; __syncthreads();
    for (int s = 512; s; s >>= 1) {
        if (tid < s) red[tid] = fmaxf(red[tid], red[tid + s]);
        __syncthreads();
    }
    mx = red[0]; __syncthreads();
    float sum = 0.f;
    for (int i = tid; i < NP; i += 1024) sum += expf(A2[h * NP + i] - mx);
    red[tid] = sum; __syncthreads();
    for (int s = 512; s; s >>= 1) {
        if (tid < s) red[tid] += red[tid + s];
        __syncthreads();
    }
    float inv = 1.f / red[0];
    for (int i = tid; i < NP; i += 1024) Wsm[h * NP + i] = expf(A2[h * NP + i] - mx) * inv;
}

// t[h][c] = sum_p Wsm[h][p] * K[c][p]    (one wave per c, all 8 heads)
__global__ __launch_bounds__(256) void k_t(const float* __restrict__ K,
                                           const float* __restrict__ Wsm,
                                           float* __restrict__ t)
{
    int wid = threadIdx.x >> 6, lane = threadIdx.x & 63;
    int c = blockIdx.x * 4 + wid;
    float acc[8] = {};
    for (int p = lane; p < NP; p += 64) {
        float kv = K[c * NP + p];
        #pragma unroll
        for (int h = 0; h < 8; h++) acc[h] += kv * Wsm[h * NP + p];
    }
    #pragma unroll
    for (int h = 0; h < 8; h++) {
        #pragma unroll
        for (int off = 32; off; off >>= 1) acc[h] += __shfl_down(acc[h], off);
    }
    if (lane == 0) {
        #pragma unroll
        for (int h = 0; h < 8; h++) t[h * 512 + c] = acc[h];
    }
}

// x[hd] = sum_c t[h][c]*Wv[hd][c] + bv[hd]   (softmax weights sum to 1)
__global__ __launch_bounds__(256) void k_x(const float* __restrict__ t,
                                           const float* __restrict__ Wv,
                                           const float* __restrict__ bv,
                                           float* __restrict__ x)
{
    int wid = threadIdx.x >> 6, lane = threadIdx.x & 63;
    int hd = blockIdx.x * 4 + wid;
    int h = hd >> 9;
    float s = 0.f;
    for (int c = lane; c < 512; c += 64) s += t[h * 512 + c] * Wv[hd * 512 + c];
    #pragma unroll
    for (int off = 32; off; off >>= 1) s += __shfl_down(s, off);
    if (lane == 0) x[hd] = s + bv[hd];
}

__global__ __launch_bounds__(256) void k_out(const float* __restrict__ x,
                                             const float* __restrict__ Wo,
                                             const float* __restrict__ bo,
                                             float* __restrict__ out)
{
    int wid = threadIdx.x >> 6, lane = threadIdx.x & 63;
    int j = blockIdx.x * 4 + wid;
    float s = 0.f;
    for (int i = lane; i < 4096; i += 64) s += x[i] * Wo[j * 4096 + i];
    #pragma unroll
    for (int off = 32; off; off >>= 1) s += __shfl_down(s, off);
    if (lane == 0) out[j] = s + bo[j];
}

extern "C" void kernel_launch(void* const* d_in, const int* in_sizes, int n_in,
                              void* d_out, int out_size, void* d_ws, size_t ws_size,
                              hipStream_t stream)
{
    (void)in_sizes; (void)n_in; (void)out_size; (void)ws_size;
    const float* Q    = (const float*)d_in[0];
    const float* K    = (const float*)d_in[1];
    const float* Wq   = (const float*)d_in[2];
    const float* bq   = (const float*)d_in[3];
    const float* Wk   = (const float*)d_in[4];
    const float* bk   = (const float*)d_in[5];
    const float* Wv   = (const float*)d_in[6];
    const float* bv   = (const float*)d_in[7];
    const float* Wo   = (const float*)d_in[8];
    const float* bo   = (const float*)d_in[9];
    const float* amp1 = (const float*)d_in[10];
    const float* amp2 = (const float*)d_in[11];
    const float* amp3 = (const float*)d_in[12];
    const float* pha1 = (const float*)d_in[13];
    const float* pha2 = (const float*)d_in[14];
    const float* pha3 = (const float*)d_in[15];
    const float* Wd1  = (const float*)d_in[16];
    const float* bd1  = (const float*)d_in[17];
    const float* Wd2  = (const float*)d_in[18];
    const float* bd2  = (const float*)d_in[19];
    float* out = (float*)d_out;

    float* ws  = (float*)d_ws;
    float* q   = ws;  ws += 4096;
    float* qkp = ws;  ws += 8 * 8 * 512;    // 32768
    float* qb  = ws;  ws += 64;
    float* Ap  = ws;  ws += 8 * 8 * NP;     // 270400
    float* f0  = ws;  ws += 512 * NP;       // 2163200
    float* y2  = ws;  ws += 512 * NP;       // 2163200
    float* f2  = ws;  ws += 8 * NP;         // 33800
    float* Fa  = ws;  ws += 8 * PR;         // 17160
    float* Fp  = ws;  ws += 8 * PR;         // 17160
    float* A2  = ws;  ws += 8 * NP;         // 33800
    float* wsm = ws;  ws += 8 * NP;         // 33800
    float* tt  = ws;  ws += 4096;
    float* xx  = ws;  ws += 4096;
    // total ~19.1 MB of workspace

    // attention logits path (algebraically collapsed: never materialize k)
    k_q<<<1024, 256, 0, stream>>>(Q, Wq, bq, q);
    k_qk<<<dim3(2, 8, 8), 256, 0, stream>>>(q, Wk, qkp);
    k_qb<<<1, 512, 0, stream>>>(q, bk, qb);
    k_alogits<<<dim3(17, 8), 256, 0, stream>>>(qkp, K, Ap);

    // two filter branches (sequential, reuse f0/y2/f2)
    for (int br = 0; br < 2; br++) {
        const float* w1 = br ? pha1 : amp1;
        const float* w2 = br ? pha2 : amp2;
        const float* w3 = br ? pha3 : amp3;
        const float* Wd = br ? Wd2 : Wd1;
        const float* bd = br ? bd2 : bd1;
        float* Fo = br ? Fp : Fa;
        k_conv1x1<<<dim3(67, 8), 256, 0, stream>>>(w1, K, f0);
        k_conv3x3<<<dim3(67, 8), 256, 0, stream>>>(w2, f0, y2);
        k_conv8<<<17, 256, 0, stream>>>(w3, y2, f2);
        k_down<<<537, 256, 0, stream>>>(f2, Wd, bd, Fo);
    }

    // FFT modulation + softmax + output path (collapsed: never materialize v)
    k_fft<<<8, 1024, 0, stream>>>(Ap, qb, Fa, Fp, A2);
    k_softmax<<<8, 1024, 0, stream>>>(A2, wsm);
    k_t<<<128, 256, 0, stream>>>(K, wsm, tt);
    k_x<<<1024, 256, 0, stream>>>(tt, Wv, bv, xx);
    k_out<<<128, 256, 0, stream>>>(xx, Wo, bo, out);
}

// Round 2
// 530.937 us; speedup vs baseline: 3.2773x; 3.2773x over previous
//
#include <hip/hip_runtime.h>
#include <hip/hip_bf16.h>

#define NP 4225      // 65*65 spatial positions
#define PR 2145      // 65*33 rfft bins

typedef __attribute__((ext_vector_type(8))) short short8;    // 8 bf16 (4 VGPRs)
typedef __attribute__((ext_vector_type(4))) float f32x4;
typedef __attribute__((ext_vector_type(4))) unsigned int u32x4;

__device__ inline float bf2f(unsigned short u) {
    union { unsigned int i; float f; } x; x.i = ((unsigned int)u) << 16; return x.f;
}
__device__ inline unsigned short f2bf(float f) {   // RNE
    union { float f; unsigned int i; } x; x.f = f;
    unsigned int r = x.i + 0x7fff + ((x.i >> 16) & 1);
    return (unsigned short)(r >> 16);
}

// ---------------- small projection kernels ----------------

__global__ __launch_bounds__(256) void k_q(const float* __restrict__ Q,
                                           const float* __restrict__ Wq,
                                           const float* __restrict__ bq,
                                           float* __restrict__ qv)
{
    int wid = threadIdx.x >> 6, lane = threadIdx.x & 63;
    int j = blockIdx.x * 4 + wid;
    float s = 0.f;
    for (int i = lane; i < 512; i += 64) s += Q[i] * Wq[j * 512 + i];
    #pragma unroll
    for (int off = 32; off; off >>= 1) s += __shfl_down(s, off);
    if (lane == 0) qv[j] = s + bq[j];
}

// qk[h][c] = sum_d q[h,d]*Wk[h*512+d, c]
__global__ __launch_bounds__(256) void k_qk2(const float* __restrict__ q,
                                             const float* __restrict__ Wk,
                                             float* __restrict__ qk)
{
    int c = blockIdx.x * 256 + threadIdx.x;  // 0..511
    int h = blockIdx.y;
    __shared__ float qs[512];
    for (int i = threadIdx.x; i < 512; i += 256) qs[i] = q[h * 512 + i];
    __syncthreads();
    float s = 0.f;
    for (int d = 0; d < 512; d++) s += qs[d] * Wk[(size_t)(h * 512 + d) * 512 + c];
    qk[h * 512 + c] = s;
}

__global__ __launch_bounds__(512) void k_qb(const float* __restrict__ q,
                                            const float* __restrict__ bk,
                                            float* __restrict__ qb)
{
    int h = threadIdx.x >> 6, lane = threadIdx.x & 63;
    float s = 0.f;
    for (int d = lane; d < 512; d += 64) s += q[h * 512 + d] * bk[h * 512 + d];
    #pragma unroll
    for (int off = 32; off; off >>= 1) s += __shfl_down(s, off);
    if (lane == 0) qb[h] = s;
}

// A[h][p] = (sum_c qk[h,c]*K[c,p] + qb[h]) / sqrt(512)
__global__ __launch_bounds__(256) void k_alogits2(const float* __restrict__ qk,
                                                  const float* __restrict__ qb,
                                                  const float* __restrict__ K,
                                                  float* __restrict__ A)
{
    __shared__ float qs[8 * 512];
    int tid = threadIdx.x;
    for (int i = tid; i < 4096; i += 256) qs[i] = qk[i];
    __syncthreads();
    int p = blockIdx.x * 256 + tid;
    bool ok = p < NP;
    float acc[8] = {};
    for (int c = 0; c < 512; c++) {
        float kv = ok ? K[(size_t)c * NP + p] : 0.f;
        #pragma unroll
        for (int h = 0; h < 8; h++) acc[h] += qs[h * 512 + c] * kv;
    }
    const float sc = 0.04419417382415922f;  // 1/sqrt(512)
    if (ok) {
        #pragma unroll
        for (int h = 0; h < 8; h++) A[h * NP + p] = (acc[h] + qb[h]) * sc;
    }
}

// ---------------- weight prep ----------------

__global__ __launch_bounds__(256) void k_cast(const float* __restrict__ in,
                                              unsigned short* __restrict__ out, int n)
{
    int i = blockIdx.x * 256 + threadIdx.x;
    if (i < n) out[i] = f2bf(in[i]);
}

// amp2 (m, c, 3, 3) fp32 -> w2b[m][tap*512 + c] bf16
__global__ __launch_bounds__(256) void k_packW2(const float* __restrict__ W,
                                                unsigned short* __restrict__ o)
{
    int i = blockIdx.x * 256 + threadIdx.x;   // over 512*512
    int m = i >> 9, c = i & 511;
    const float* src = W + (size_t)i * 9;
    #pragma unroll
    for (int t = 0; t < 9; t++) o[(size_t)m * 4608 + t * 512 + c] = f2bf(src[t]);
}

// ---------------- MFMA conv kernels ----------------
// GEMM-T: C[p][m] = sum_k A[p][k] * B[m][k]; 64(p) x 128(m) tile, 4 waves (2x2),
// wave tile 32x64 = 2x4 frags of 16x16, K-chunk 64 (2 mfma k-steps).

// conv1x1: A = K^T (cast from fp32 K[c][p] via LDS transpose), B = w1b[m][k].
// Writes f0rb = bf16(C), f0tb = bf16(relu(C)).
__global__ __launch_bounds__(256) void k_conv1T(const float* __restrict__ K,
                                                const unsigned short* __restrict__ w1b,
                                                unsigned short* __restrict__ f0rb,
                                                unsigned short* __restrict__ f0tb)
{
    __shared__ unsigned short As[64 * 64];
    __shared__ unsigned short Bs[128 * 64];
    int tid = threadIdx.x;
    int bm = blockIdx.x * 64;       // p tile
    int bn = blockIdx.y * 128;      // m tile
    int lane = tid & 63;
    int w = tid >> 6;
    int wp = (w >> 1) * 32, wm = (w & 1) * 64;
    int rb = tid >> 1, hb = tid & 1;          // B staging map
    int ct = tid >> 4, p4 = (tid & 15) * 4;   // A staging map (16 c-rows/pass)

    f32x4 acc[2][4];
    #pragma unroll
    for (int i = 0; i < 2; i++)
        #pragma unroll
        for (int j = 0; j < 4; j++) acc[i][j] = (f32x4){0.f, 0.f, 0.f, 0.f};

    for (int kc = 0; kc < 8; kc++) {
        int c0 = kc * 64;
        // stage A: transpose-cast K[c0..c0+63][bm..bm+63]
        #pragma unroll
        for (int pass = 0; pass < 4; pass++) {
            int cl = pass * 16 + ct;
            const float* src = K + (size_t)(c0 + cl) * NP + bm + p4;
            #pragma unroll
            for (int j = 0; j < 4; j++) {
                int p = bm + p4 + j;
                float v = (p < NP) ? src[j] : 0.f;
                int row = p4 + j;
                int byte = (row * 128 + cl * 2) ^ ((row & 7) << 4);
                *(unsigned short*)((char*)As + byte) = f2bf(v);
            }
        }
        // stage B: w1b rows
        {
            const unsigned short* brow = w1b + (size_t)(bn + rb) * 512 + c0 + hb * 32;
            int bb = rb * 128 + hb * 64;
            #pragma unroll
            for (int j = 0; j < 4; j++) {
                u32x4 bv = *(const u32x4*)(brow + j * 8);
                *(u32x4*)((char*)Bs + ((bb + j * 16) ^ ((rb & 7) << 4))) = bv;
            }
        }
        __syncthreads();
        #pragma unroll
        for (int ks = 0; ks < 2; ks++) {
            short8 af[2], bfr[4];
            #pragma unroll
            for (int fi = 0; fi < 2; fi++) {
                int row = wp + fi * 16 + (lane & 15);
                int byte = row * 128 + ((ks * 64 + ((lane >> 4) * 16)) ^ ((row & 7) << 4));
                af[fi] = *(const short8*)((char*)As + byte);
            }
            #pragma unroll
            for (int fj = 0; fj < 4; fj++) {
                int n = wm + fj * 16 + (lane & 15);
                int byte = n * 128 + ((ks * 64 + ((lane >> 4) * 16)) ^ ((n & 7) << 4));
                bfr[fj] = *(const short8*)((char*)Bs + byte);
            }
            #pragma unroll
            for (int fi = 0; fi < 2; fi++)
                #pragma unroll
                for (int fj = 0; fj < 4; fj++)
                    acc[fi][fj] = __builtin_amdgcn_mfma_f32_16x16x32_bf16(af[fi], bfr[fj], acc[fi][fj], 0, 0, 0);
        }
        __syncthreads();
    }
    #pragma unroll
    for (int fi = 0; fi < 2; fi++)
        #pragma unroll
        for (int r = 0; r < 4; r++) {
            int p = bm + wp + fi * 16 + (lane >> 4) * 4 + r;
            if (p >= NP) continue;
            #pragma unroll
            for (int fj = 0; fj < 4; fj++) {
                int m = bn + wm + fj * 16 + (lane & 15);
                float v = acc[fi][fj][r];
                f0rb[(size_t)p * 512 + m] = f2bf(v);
                f0tb[(size_t)p * 512 + m] = f2bf(fmaxf(v, 0.f));
            }
        }
}

// conv3x3: A = f0tb[p'][c] (tap-shifted rows, row-granular masking), B = w2b[m][tap*512+c].
// C += residual bf2f(f0rb); writes ytb = bf16(relu(C)).
__global__ __launch_bounds__(256) void k_conv3T(const unsigned short* __restrict__ f0tb,
                                                const unsigned short* __restrict__ w2b,
                                                const unsigned short* __restrict__ f0rb,
                                                unsigned short* __restrict__ ytb)
{
    __shared__ unsigned short As[64 * 64];
    __shared__ unsigned short Bs[128 * 64];
    int tid = threadIdx.x;
    int bm = blockIdx.x * 64;
    int bn = blockIdx.y * 128;
    int lane = tid & 63;
    int w = tid >> 6;
    int wp = (w >> 1) * 32, wm = (w & 1) * 64;
    int ra = tid >> 2, sa = tid & 3;   // A staging: row, 16-elem segment
    int rb = tid >> 1, hb = tid & 1;   // B staging
    int pA = bm + ra;
    int py = pA / 65, px = pA - py * 65;

    f32x4 acc[2][4];
    #pragma unroll
    for (int i = 0; i < 2; i++)
        #pragma unroll
        for (int j = 0; j < 4; j++) acc[i][j] = (f32x4){0.f, 0.f, 0.f, 0.f};

    for (int tap = 0; tap < 9; tap++) {
        int ky = tap / 3 - 1, kx = tap % 3 - 1;
        int sy = py + ky, sx = px + kx;
        bool valid = (pA < NP) && sy >= 0 && sy < 65 && sx >= 0 && sx < 65;
        const unsigned short* arow = f0tb + (size_t)(pA + ky * 65 + kx) * 512;
        const unsigned short* bbase = w2b + tap * 512;
        for (int kc = 0; kc < 8; kc++) {
            u32x4 av0 = {0, 0, 0, 0}, av1 = {0, 0, 0, 0};
            if (valid) {
                av0 = *(const u32x4*)(arow + kc * 64 + sa * 16);
                av1 = *(const u32x4*)(arow + kc * 64 + sa * 16 + 8);
            }
            int ab = ra * 128 + sa * 32;
            *(u32x4*)((char*)As + ((ab) ^ ((ra & 7) << 4)))      = av0;
            *(u32x4*)((char*)As + ((ab + 16) ^ ((ra & 7) << 4))) = av1;
            {
                const unsigned short* brow = bbase + (size_t)(bn + rb) * 4608 + kc * 64 + hb * 32;
                int bb = rb * 128 + hb * 64;
                #pragma unroll
                for (int j = 0; j < 4; j++) {
                    u32x4 bv = *(const u32x4*)(brow + j * 8);
                    *(u32x4*)((char*)Bs + ((bb + j * 16) ^ ((rb & 7) << 4))) = bv;
                }
            }
            __syncthreads();
            #pragma unroll
            for (int ks = 0; ks < 2; ks++) {
                short8 af[2], bfr[4];
                #pragma unroll
                for (int fi = 0; fi < 2; fi++) {
                    int row = wp + fi * 16 + (lane & 15);
                    int byte = row * 128 + ((ks * 64 + ((lane >> 4) * 16)) ^ ((row & 7) << 4));
                    af[fi] = *(const short8*)((char*)As + byte);
                }
                #pragma unroll
                for (int fj = 0; fj < 4; fj++) {
                    int n = wm + fj * 16 + (lane & 15);
                    int byte = n * 128 + ((ks * 64 + ((lane >> 4) * 16)) ^ ((n & 7) << 4));
                    bfr[fj] = *(const short8*)((char*)Bs + byte);
                }
                #pragma unroll
                for (int fi = 0; fi < 2; fi++)
                    #pragma unroll
                    for (int fj = 0; fj < 4; fj++)
                        acc[fi][fj] = __builtin_amdgcn_mfma_f32_16x16x32_bf16(af[fi], bfr[fj], acc[fi][fj], 0, 0, 0);
            }
            __syncthreads();
        }
    }
    #pragma unroll
    for (int fi = 0; fi < 2; fi++)
        #pragma unroll
        for (int r = 0; r < 4; r++) {
            int p = bm + wp + fi * 16 + (lane >> 4) * 4 + r;
            if (p >= NP) continue;
            #pragma unroll
            for (int fj = 0; fj < 4; fj++) {
                int m = bn + wm + fj * 16 + (lane & 15);
                float v = acc[fi][fj][r] + bf2f(f0rb[(size_t)p * 512 + m]);
                ytb[(size_t)p * 512 + m] = f2bf(fmaxf(v, 0.f));
            }
        }
}

// conv8: F2[h][p] = relu(sum_c w3[h][c] * ytb[p][c])   (ytb already relu'd)
__global__ __launch_bounds__(256) void k_conv8T(const float* __restrict__ w3,
                                                const unsigned short* __restrict__ Yt,
                                                float* __restrict__ F2)
{
    __shared__ float wf[8 * 512];
    int tid = threadIdx.x;
    for (int i = tid; i < 4096; i += 256) wf[i] = w3[i];
    __syncthreads();
    int pl = tid >> 2, qc = tid & 3;
    int p = blockIdx.x * 64 + pl;
    int pc = (p < NP) ? p : NP - 1;
    const unsigned short* row = Yt + (size_t)pc * 512 + qc * 128;
    float acc[8] = {};
    for (int cc = 0; cc < 128; cc += 8) {
        u32x4 v = *(const u32x4*)(row + cc);
        unsigned short e[8];
        *(u32x4*)e = v;
        #pragma unroll
        for (int j = 0; j < 8; j++) {
            float x = bf2f(e[j]);
            int c = qc * 128 + cc + j;
            #pragma unroll
            for (int h = 0; h < 8; h++) acc[h] += wf[h * 512 + c] * x;
        }
    }
    #pragma unroll
    for (int h = 0; h < 8; h++) {
        acc[h] += __shfl_xor(acc[h], 1);
        acc[h] += __shfl_xor(acc[h], 2);
    }
    if (qc == 0 && p < NP) {
        #pragma unroll
        for (int h = 0; h < 8; h++) F2[h * NP + p] = fmaxf(acc[h], 0.f);
    }
}

// down-proj: Fo[h][j] = sum_p F2[h][p] * Wd[j][p] + bd[j]
__global__ __launch_bounds__(256) void k_down(const float* __restrict__ F2,
                                              const float* __restrict__ Wd,
                                              const float* __restrict__ bd,
                                              float* __restrict__ Fo)
{
    int wid = threadIdx.x >> 6, lane = threadIdx.x & 63;
    int j = blockIdx.x * 4 + wid;
    if (j >= PR) return;
    const float* wr = Wd + (size_t)j * NP;
    float acc[8] = {};
    for (int p = lane; p < NP; p += 64) {
        float wv = wr[p];
        #pragma unroll
        for (int h = 0; h < 8; h++) acc[h] += wv * F2[h * NP + p];
    }
    #pragma unroll
    for (int h = 0; h < 8; h++) {
        #pragma unroll
        for (int off = 32; off; off >>= 1) acc[h] += __shfl_down(acc[h], off);
    }
    if (lane == 0) {
        float b = bd[j];
        #pragma unroll
        for (int h = 0; h < 8; h++) Fo[h * PR + j] = acc[h] + b;
    }
}

// ---------------- FFT / modulation / inverse ----------------

__global__ __launch_bounds__(1024) void k_fft(const float* __restrict__ A,
                                              const float* __restrict__ Fa,
                                              const float* __restrict__ Fp,
                                              float* __restrict__ A2)
{
    int h = blockIdx.x;
    int tid = threadIdx.x;
    __shared__ float As[65][65];
    __shared__ float Tr[65][33], Ti[65][33];
    __shared__ float Br[65][33], Bi[65][33];
    __shared__ double ctd[65], snd[65];
    __shared__ float ct[65], st[65];
    if (tid < 65) {
        double ang = 6.283185307179586476925286766559 * (double)tid / 65.0;
        double cv = cos(ang), sv = sin(ang);
        ctd[tid] = cv; snd[tid] = sv;
        ct[tid] = (float)cv; st[tid] = (float)sv;
    }
    for (int i = tid; i < NP; i += 1024) As[i / 65][i % 65] = A[h * NP + i];
    __syncthreads();
    for (int o = tid; o < PR; o += 1024) {
        int y = o / 33, v = o % 33;
        double sr = 0.0, si = 0.0;
        for (int x = 0; x < 65; x++) {
            int m = (v * x) % 65;
            double a = (double)As[y][x];
            sr += a * ctd[m];
            si -= a * snd[m];
        }
        Tr[y][v] = (float)sr; Ti[y][v] = (float)si;
    }
    __syncthreads();
    for (int o = tid; o < PR; o += 1024) {
        int u = o / 33, v = o % 33;
        double sr = 0.0, si = 0.0;
        for (int y = 0; y < 65; y++) {
            int m = (u * y) % 65;
            double c = ctd[m], s = snd[m];
            double tr = (double)Tr[y][v], ti = (double)Ti[y][v];
            sr += tr * c + ti * s;
            si += ti * c - tr * s;
        }
        float re = (float)sr, im = (float)si;
        float mag = sqrtf(re * re + im * im);
        float ang = atan2f(im, re);
        float amp = Fa[h * PR + o] * mag;
        float ph  = Fp[h * PR + o] * ang;
        float sn, cn;
        sincosf(ph, &sn, &cn);
        Br[u][v] = amp * cn;
        Bi[u][v] = amp * sn;
    }
    __syncthreads();
    for (int o = tid; o < PR; o += 1024) {
        int y = o / 33, v = o % 33;
        float sr = 0.f, si = 0.f;
        for (int u = 0; u < 65; u++) {
            int m = (u * y) % 65;
            float c = ct[m], s = st[m];
            float ar = Br[u][v], ai = Bi[u][v];
            sr += ar * c - ai * s;
            si += ai * c + ar * s;
        }
        Tr[y][v] = sr; Ti[y][v] = si;
    }
    __syncthreads();
    for (int o = tid; o < NP; o += 1024) {
        int y = o / 65, x = o % 65;
        float s = Tr[y][0];
        for (int v = 1; v < 33; v++) {
            int m = (v * x) % 65;
            s += 2.f * (Tr[y][v] * ct[m] - Ti[y][v] * st[m]);
        }
        A2[h * NP + o] = s * (1.f / 4225.f);
    }
}

__global__ __launch_bounds__(1024) void k_softmax(const float* __restrict__ A2,
                                                  float* __restrict__ Wsm)
{
    int h = blockIdx.x, tid = threadIdx.x;
    __shared__ float red[1024];
    float mx = -3.0e38f;
    for (int i = tid; i < NP; i += 1024) mx = fmaxf(mx, A2[h * NP + i]);
    red[tid] = mx; __syncthreads();
    for (int s = 512; s; s >>= 1) {
        if (tid < s) red[tid] = fmaxf(red[tid], red[tid + s]);
        __syncthreads();
    }
    mx = red[0]; __syncthreads();
    float sum = 0.f;
    for (int i = tid; i < NP; i += 1024) sum += expf(A2[h * NP + i] - mx);
    red[tid] = sum; __syncthreads();
    for (int s = 512; s; s >>= 1) {
        if (tid < s) red[tid] += red[tid + s];
        __syncthreads();
    }
    float inv = 1.f / red[0];
    for (int i = tid; i < NP; i += 1024) Wsm[h * NP + i] = expf(A2[h * NP + i] - mx) * inv;
}

__global__ __launch_bounds__(256) void k_t(const float* __restrict__ K,
                                           const float* __restrict__ Wsm,
                                           float* __restrict__ t)
{
    int wid = threadIdx.x >> 6, lane = threadIdx.x & 63;
    int c = blockIdx.x * 4 + wid;
    float acc[8] = {};
    for (int p = lane; p < NP; p += 64) {
        float kv = K[(size_t)c * NP + p];
        #pragma unroll
        for (int h = 0; h < 8; h++) acc[h] += kv * Wsm[h * NP + p];
    }
    #pragma unroll
    for (int h = 0; h < 8; h++) {
        #pragma unroll
        for (int off = 32; off; off >>= 1) acc[h] += __shfl_down(acc[h], off);
    }
    if (lane == 0) {
        #pragma unroll
        for (int h = 0; h < 8; h++) t[h * 512 + c] = acc[h];
    }
}

__global__ __launch_bounds__(256) void k_x(const float* __restrict__ t,
                                           const float* __restrict__ Wv,
                                           const float* __restrict__ bv,
                                           float* __restrict__ x)
{
    int wid = threadIdx.x >> 6, lane = threadIdx.x & 63;
    int hd = blockIdx.x * 4 + wid;
    int h = hd >> 9;
    float s = 0.f;
    for (int c = lane; c < 512; c += 64) s += t[h * 512 + c] * Wv[(size_t)hd * 512 + c];
    #pragma unroll
    for (int off = 32; off; off >>= 1) s += __shfl_down(s, off);
    if (lane == 0) x[hd] = s + bv[hd];
}

__global__ __launch_bounds__(256) void k_out(const float* __restrict__ x,
                                             const float* __restrict__ Wo,
                                             const float* __restrict__ bo,
                                             float* __restrict__ out)
{
    int wid = threadIdx.x >> 6, lane = threadIdx.x & 63;
    int j = blockIdx.x * 4 + wid;
    float s = 0.f;
    for (int i = lane; i < 4096; i += 64) s += x[i] * Wo[(size_t)j * 4096 + i];
    #pragma unroll
    for (int off = 32; off; off >>= 1) s += __shfl_down(s, off);
    if (lane == 0) out[j] = s + bo[j];
}

extern "C" void kernel_launch(void* const* d_in, const int* in_sizes, int n_in,
                              void* d_out, int out_size, void* d_ws, size_t ws_size,
                              hipStream_t stream)
{
    (void)in_sizes; (void)n_in; (void)out_size; (void)ws_size;
    const float* Q    = (const float*)d_in[0];
    const float* K    = (const float*)d_in[1];
    const float* Wq   = (const float*)d_in[2];
    const float* bq   = (const float*)d_in[3];
    const float* Wk   = (const float*)d_in[4];
    const float* bk   = (const float*)d_in[5];
    const float* Wv   = (const float*)d_in[6];
    const float* bv   = (const float*)d_in[7];
    const float* Wo   = (const float*)d_in[8];
    const float* bo   = (const float*)d_in[9];
    const float* amp1 = (const float*)d_in[10];
    const float* amp2 = (const float*)d_in[11];
    const float* amp3 = (const float*)d_in[12];
    const float* pha1 = (const float*)d_in[13];
    const float* pha2 = (const float*)d_in[14];
    const float* pha3 = (const float*)d_in[15];
    const float* Wd1  = (const float*)d_in[16];
    const float* bd1  = (const float*)d_in[17];
    const float* Wd2  = (const float*)d_in[18];
    const float* bd2  = (const float*)d_in[19];
    float* out = (float*)d_out;

    char* w = (char*)d_ws;
    auto alloc = [&](size_t bytes) { char* p = w; w += (bytes + 255) & ~(size_t)255; return p; };
    float* qv   = (float*)alloc(4096 * 4);
    float* qk   = (float*)alloc(4096 * 4);
    float* qb   = (float*)alloc(64 * 4);
    float* A    = (float*)alloc(8 * NP * 4);
    unsigned short* w1b  = (unsigned short*)alloc((size_t)512 * 512 * 2);
    unsigned short* w2b  = (unsigned short*)alloc((size_t)512 * 4608 * 2);
    unsigned short* f0rb = (unsigned short*)alloc((size_t)NP * 512 * 2);
    unsigned short* f0tb = (unsigned short*)alloc((size_t)NP * 512 * 2);
    unsigned short* ytb  = (unsigned short*)alloc((size_t)NP * 512 * 2);
    float* F2   = (float*)alloc(8 * NP * 4);
    float* Fa   = (float*)alloc(8 * PR * 4);
    float* Fp   = (float*)alloc(8 * PR * 4);
    float* A2   = (float*)alloc(8 * NP * 4);
    float* wsm  = (float*)alloc(8 * NP * 4);
    float* tt   = (float*)alloc(4096 * 4);
    float* xx   = (float*)alloc(4096 * 4);
    // total ~19.0 MB

    // attention logits path
    k_q<<<1024, 256, 0, stream>>>(Q, Wq, bq, qv);
    k_qk2<<<dim3(2, 8), 256, 0, stream>>>(qv, Wk, qk);
    k_qb<<<1, 512, 0, stream>>>(qv, bk, qb);
    k_alogits2<<<17, 256, 0, stream>>>(qk, qb, K, A);

    // two filter branches
    for (int br = 0; br < 2; br++) {
        const float* w1 = br ? pha1 : amp1;
        const float* w2 = br ? pha2 : amp2;
        const float* w3 = br ? pha3 : amp3;
        const float* Wd = br ? Wd2 : Wd1;
        const float* bd = br ? bd2 : bd1;
        float* Fo = br ? Fp : Fa;
        k_cast<<<1024, 256, 0, stream>>>(w1, w1b, 512 * 512);
        k_packW2<<<1024, 256, 0, stream>>>(w2, w2b);
        k_conv1T<<<dim3(67, 4), 256, 0, stream>>>(K, w1b, f0rb, f0tb);
        k_conv3T<<<dim3(67, 4), 256, 0, stream>>>(f0tb, w2b, f0rb, ytb);
        k_conv8T<<<67, 256, 0, stream>>>(w3, ytb, F2);
        k_down<<<537, 256, 0, stream>>>(F2, Wd, bd, Fo);
    }

    // FFT modulation + softmax + output path
    k_fft<<<8, 1024, 0, stream>>>(A, Fa, Fp, A2);
    k_softmax<<<8, 1024, 0, stream>>>(A2, wsm);
    k_t<<<128, 256, 0, stream>>>(K, wsm, tt);
    k_x<<<1024, 256, 0, stream>>>(tt, Wv, bv, xx);
    k_out<<<128, 256, 0, stream>>>(xx, Wo, bo, out);
}

// Round 3
// 370.898 us; speedup vs baseline: 4.6915x; 1.4315x over previous
//
#include <hip/hip_runtime.h>
#include <hip/hip_bf16.h>

#define NP 4225      // 65*65 spatial positions
#define PR 2145      // 65*33 rfft bins

typedef __attribute__((ext_vector_type(8))) short short8;    // 8 bf16 (4 VGPRs)
typedef __attribute__((ext_vector_type(4))) float f32x4;
typedef __attribute__((ext_vector_type(4))) unsigned int u32x4;
typedef unsigned short ushort_t;

__device__ inline float bf2f(unsigned short u) {
    union { unsigned int i; float f; } x; x.i = ((unsigned int)u) << 16; return x.f;
}
__device__ inline unsigned short f2bf(float f) {   // RNE
    union { float f; unsigned int i; } x; x.f = f;
    unsigned int r = x.i + 0x7fff + ((x.i >> 16) & 1);
    return (unsigned short)(r >> 16);
}

// ---------------- small projection kernels ----------------

__global__ __launch_bounds__(256) void k_q(const float* __restrict__ Q,
                                           const float* __restrict__ Wq,
                                           const float* __restrict__ bq,
                                           float* __restrict__ qv)
{
    int wid = threadIdx.x >> 6, lane = threadIdx.x & 63;
    int j = blockIdx.x * 4 + wid;
    float s = 0.f;
    for (int i = lane; i < 512; i += 64) s += Q[i] * Wq[j * 512 + i];
    #pragma unroll
    for (int off = 32; off; off >>= 1) s += __shfl_down(s, off);
    if (lane == 0) qv[j] = s + bq[j];
}

// qkp[dz][h][c] = sum over 32 d of q[h, dz*32+d] * Wk[h*512+dz*32+d, c]
__global__ __launch_bounds__(256) void k_qk3(const float* __restrict__ qv,
                                             const float* __restrict__ Wk,
                                             float* __restrict__ qkp)
{
    int c = blockIdx.x * 256 + threadIdx.x;
    int h = blockIdx.y, dz = blockIdx.z;
    __shared__ float qs[32];
    if (threadIdx.x < 32) qs[threadIdx.x] = qv[h * 512 + dz * 32 + threadIdx.x];
    __syncthreads();
    float s = 0.f;
    #pragma unroll 8
    for (int d = 0; d < 32; d++)
        s += qs[d] * Wk[(size_t)(h * 512 + dz * 32 + d) * 512 + c];
    qkp[(dz * 8 + h) * 512 + c] = s;
}

__global__ __launch_bounds__(512) void k_qb(const float* __restrict__ q,
                                            const float* __restrict__ bk,
                                            float* __restrict__ qb)
{
    int h = threadIdx.x >> 6, lane = threadIdx.x & 63;
    float s = 0.f;
    for (int d = lane; d < 512; d += 64) s += q[h * 512 + d] * bk[h * 512 + d];
    #pragma unroll
    for (int off = 32; off; off >>= 1) s += __shfl_down(s, off);
    if (lane == 0) qb[h] = s;
}

// Ap[cz][h][p] partials: sum over 16 c of qk[h,c]*K[c,p]
__global__ __launch_bounds__(256) void k_alogits3(const float* __restrict__ qkp,
                                                  const float* __restrict__ K,
                                                  float* __restrict__ Ap)
{
    __shared__ float sqk[8][16];
    int tid = threadIdx.x;
    int cz = blockIdx.y;
    if (tid < 128) {
        int hh = tid >> 4, cc = tid & 15;
        float s = 0.f;
        #pragma unroll
        for (int dz = 0; dz < 16; dz++) s += qkp[(dz * 8 + hh) * 512 + cz * 16 + cc];
        sqk[hh][cc] = s;
    }
    __syncthreads();
    int p = blockIdx.x * 256 + tid;
    bool ok = p < NP;
    float acc[8] = {};
    #pragma unroll
    for (int cc = 0; cc < 16; cc++) {
        float kv = ok ? K[(size_t)(cz * 16 + cc) * NP + p] : 0.f;
        #pragma unroll
        for (int h = 0; h < 8; h++) acc[h] += sqk[h][cc] * kv;
    }
    if (ok) {
        #pragma unroll
        for (int h = 0; h < 8; h++) Ap[(size_t)(cz * 8 + h) * NP + p] = acc[h];
    }
}

// A[h][p] = (sum_cz Ap[cz][h][p] + qb[h]) / sqrt(512)
__global__ __launch_bounds__(256) void k_areduce(const float* __restrict__ Ap,
                                                 const float* __restrict__ qb,
                                                 float* __restrict__ A)
{
    int p = blockIdx.x * 256 + threadIdx.x;
    int h = blockIdx.y;
    if (p >= NP) return;
    float s = 0.f;
    #pragma unroll 8
    for (int cz = 0; cz < 32; cz++) s += Ap[(size_t)(cz * 8 + h) * NP + p];
    const float sc = 0.04419417382415922f;
    A[h * NP + p] = (s + qb[h]) * sc;
}

// ---------------- weight prep ----------------

__global__ __launch_bounds__(256) void k_cast(const float* __restrict__ in,
                                              unsigned short* __restrict__ out, int n)
{
    int i = blockIdx.x * 256 + threadIdx.x;
    if (i < n) out[i] = f2bf(in[i]);
}

// amp2 (m, c, 3, 3) fp32 -> w2b[m][tap*512 + c] bf16
__global__ __launch_bounds__(256) void k_packW2(const float* __restrict__ W,
                                                unsigned short* __restrict__ o)
{
    int i = blockIdx.x * 256 + threadIdx.x;   // over 512*512
    int m = i >> 9, c = i & 511;
    const float* src = W + (size_t)i * 9;
    #pragma unroll
    for (int t = 0; t < 9; t++) o[(size_t)m * 4608 + t * 512 + c] = f2bf(src[t]);
}

// ---------------- MFMA conv kernels (double-buffered, T14 async stage) ----------------
// GEMM-T: C[p][m] = sum_k A[p][k] * B[m][k]; 64(p) x 128(m) tile, 4 waves (2x2),
// wave tile 32x64 = 2x4 frags of 16x16, K-chunk 64 (2 mfma k-steps).

__global__ __launch_bounds__(256) void k_conv1T(const float* __restrict__ K,
                                                const unsigned short* __restrict__ w1b,
                                                unsigned short* __restrict__ f0rb,
                                                unsigned short* __restrict__ f0tb)
{
    __shared__ unsigned short As[2][64 * 64];
    __shared__ unsigned short Bs[2][128 * 64];
    int tid = threadIdx.x;
    int bm = blockIdx.x * 64;       // p tile
    int bn = blockIdx.y * 128;      // m tile
    int lane = tid & 63;
    int w = tid >> 6;
    int wp = (w >> 1) * 32, wm = (w & 1) * 64;
    int rb = tid >> 1, hb = tid & 1;          // B staging map
    int ct = tid >> 4, p4 = (tid & 15) * 4;   // A staging map (16 c-rows/pass)

    f32x4 acc[2][4];
    #pragma unroll
    for (int i = 0; i < 2; i++)
        #pragma unroll
        for (int j = 0; j < 4; j++) acc[i][j] = (f32x4){0.f, 0.f, 0.f, 0.f};

    float areg[16];
    u32x4 breg[4];

    auto loadRegs = [&](int kc) {
        int c0 = kc * 64;
        #pragma unroll
        for (int pass = 0; pass < 4; pass++) {
            int cl = pass * 16 + ct;
            const float* src = K + (size_t)(c0 + cl) * NP + bm + p4;
            #pragma unroll
            for (int j = 0; j < 4; j++)
                areg[pass * 4 + j] = (bm + p4 + j < NP) ? src[j] : 0.f;
        }
        const unsigned short* brow = w1b + (size_t)(bn + rb) * 512 + c0 + hb * 32;
        #pragma unroll
        for (int j = 0; j < 4; j++) breg[j] = *(const u32x4*)(brow + j * 8);
    };
    auto writeS = [&](int buf) {
        #pragma unroll
        for (int pass = 0; pass < 4; pass++) {
            int cl = pass * 16 + ct;
            #pragma unroll
            for (int j = 0; j < 4; j++) {
                int row = p4 + j;
                int byte = (row * 128 + cl * 2) ^ ((row & 7) << 4);
                *(unsigned short*)((char*)As[buf] + byte) = f2bf(areg[pass * 4 + j]);
            }
        }
        int bb = rb * 128 + hb * 64;
        #pragma unroll
        for (int j = 0; j < 4; j++)
            *(u32x4*)((char*)Bs[buf] + ((bb + j * 16) ^ ((rb & 7) << 4))) = breg[j];
    };

    loadRegs(0);
    writeS(0);
    __syncthreads();
    for (int kc = 0; kc < 8; kc++) {
        if (kc < 7) loadRegs(kc + 1);
        int buf = kc & 1;
        #pragma unroll
        for (int ks = 0; ks < 2; ks++) {
            short8 af[2], bfr[4];
            #pragma unroll
            for (int fi = 0; fi < 2; fi++) {
                int row = wp + fi * 16 + (lane & 15);
                int byte = row * 128 + ((ks * 64 + ((lane >> 4) * 16)) ^ ((row & 7) << 4));
                af[fi] = *(const short8*)((char*)As[buf] + byte);
            }
            #pragma unroll
            for (int fj = 0; fj < 4; fj++) {
                int n = wm + fj * 16 + (lane & 15);
                int byte = n * 128 + ((ks * 64 + ((lane >> 4) * 16)) ^ ((n & 7) << 4));
                bfr[fj] = *(const short8*)((char*)Bs[buf] + byte);
            }
            #pragma unroll
            for (int fi = 0; fi < 2; fi++)
                #pragma unroll
                for (int fj = 0; fj < 4; fj++)
                    acc[fi][fj] = __builtin_amdgcn_mfma_f32_16x16x32_bf16(af[fi], bfr[fj], acc[fi][fj], 0, 0, 0);
        }
        if (kc < 7) writeS((kc + 1) & 1);
        __syncthreads();
    }
    #pragma unroll
    for (int fi = 0; fi < 2; fi++)
        #pragma unroll
        for (int r = 0; r < 4; r++) {
            int p = bm + wp + fi * 16 + (lane >> 4) * 4 + r;
            if (p >= NP) continue;
            #pragma unroll
            for (int fj = 0; fj < 4; fj++) {
                int m = bn + wm + fj * 16 + (lane & 15);
                float v = acc[fi][fj][r];
                f0rb[(size_t)p * 512 + m] = f2bf(v);
                f0tb[(size_t)p * 512 + m] = f2bf(fmaxf(v, 0.f));
            }
        }
}

__global__ __launch_bounds__(256) void k_conv3T(const unsigned short* __restrict__ f0tb,
                                                const unsigned short* __restrict__ w2b,
                                                const unsigned short* __restrict__ f0rb,
                                                unsigned short* __restrict__ ytb)
{
    __shared__ unsigned short As[2][64 * 64];
    __shared__ unsigned short Bs[2][128 * 64];
    int tid = threadIdx.x;
    int bm = blockIdx.x * 64;
    int bn = blockIdx.y * 128;
    int lane = tid & 63;
    int w = tid >> 6;
    int wp = (w >> 1) * 32, wm = (w & 1) * 64;
    int ra = tid >> 2, sa = tid & 3;   // A staging: row, 16-elem segment
    int rb = tid >> 1, hb = tid & 1;   // B staging
    int pA = bm + ra;
    int py = pA / 65, px = pA - py * 65;

    f32x4 acc[2][4];
    #pragma unroll
    for (int i = 0; i < 2; i++)
        #pragma unroll
        for (int j = 0; j < 4; j++) acc[i][j] = (f32x4){0.f, 0.f, 0.f, 0.f};

    u32x4 areg0, areg1, breg[4];

    auto loadRegs = [&](int it) {
        int tap = it >> 3, kc = it & 7;
        int ky = tap / 3 - 1, kx = tap % 3 - 1;
        int sy = py + ky, sx = px + kx;
        bool valid = (pA < NP) && sy >= 0 && sy < 65 && sx >= 0 && sx < 65;
        int srow = valid ? (pA + ky * 65 + kx) : 0;
        const unsigned short* arow = f0tb + (size_t)srow * 512 + kc * 64 + sa * 16;
        u32x4 a0 = *(const u32x4*)arow;
        u32x4 a1 = *(const u32x4*)(arow + 8);
        areg0 = valid ? a0 : (u32x4){0, 0, 0, 0};
        areg1 = valid ? a1 : (u32x4){0, 0, 0, 0};
        const unsigned short* brow = w2b + tap * 512 + (size_t)(bn + rb) * 4608 + kc * 64 + hb * 32;
        #pragma unroll
        for (int j = 0; j < 4; j++) breg[j] = *(const u32x4*)(brow + j * 8);
    };
    auto writeS = [&](int buf) {
        int ab = ra * 128 + sa * 32;
        *(u32x4*)((char*)As[buf] + ((ab) ^ ((ra & 7) << 4)))      = areg0;
        *(u32x4*)((char*)As[buf] + ((ab + 16) ^ ((ra & 7) << 4))) = areg1;
        int bb = rb * 128 + hb * 64;
        #pragma unroll
        for (int j = 0; j < 4; j++)
            *(u32x4*)((char*)Bs[buf] + ((bb + j * 16) ^ ((rb & 7) << 4))) = breg[j];
    };

    loadRegs(0);
    writeS(0);
    __syncthreads();
    for (int it = 0; it < 72; it++) {
        if (it < 71) loadRegs(it + 1);
        int buf = it & 1;
        #pragma unroll
        for (int ks = 0; ks < 2; ks++) {
            short8 af[2], bfr[4];
            #pragma unroll
            for (int fi = 0; fi < 2; fi++) {
                int row = wp + fi * 16 + (lane & 15);
                int byte = row * 128 + ((ks * 64 + ((lane >> 4) * 16)) ^ ((row & 7) << 4));
                af[fi] = *(const short8*)((char*)As[buf] + byte);
            }
            #pragma unroll
            for (int fj = 0; fj < 4; fj++) {
                int n = wm + fj * 16 + (lane & 15);
                int byte = n * 128 + ((ks * 64 + ((lane >> 4) * 16)) ^ ((n & 7) << 4));
                bfr[fj] = *(const short8*)((char*)Bs[buf] + byte);
            }
            #pragma unroll
            for (int fi = 0; fi < 2; fi++)
                #pragma unroll
                for (int fj = 0; fj < 4; fj++)
                    acc[fi][fj] = __builtin_amdgcn_mfma_f32_16x16x32_bf16(af[fi], bfr[fj], acc[fi][fj], 0, 0, 0);
        }
        if (it < 71) writeS((it + 1) & 1);
        __syncthreads();
    }
    #pragma unroll
    for (int fi = 0; fi < 2; fi++)
        #pragma unroll
        for (int r = 0; r < 4; r++) {
            int p = bm + wp + fi * 16 + (lane >> 4) * 4 + r;
            if (p >= NP) continue;
            #pragma unroll
            for (int fj = 0; fj < 4; fj++) {
                int m = bn + wm + fj * 16 + (lane & 15);
                float v = acc[fi][fj][r] + bf2f(f0rb[(size_t)p * 512 + m]);
                ytb[(size_t)p * 512 + m] = f2bf(fmaxf(v, 0.f));
            }
        }
}

// conv8: F2[h][p] = relu(sum_c w3[h][c] * ytb[p][c])
__global__ __launch_bounds__(256) void k_conv8T(const float* __restrict__ w3,
                                                const unsigned short* __restrict__ Yt,
                                                float* __restrict__ F2)
{
    __shared__ float wf[8 * 512];
    int tid = threadIdx.x;
    for (int i = tid; i < 4096; i += 256) wf[i] = w3[i];
    __syncthreads();
    int pl = tid >> 2, qc = tid & 3;
    int p = blockIdx.x * 64 + pl;
    int pc = (p < NP) ? p : NP - 1;
    const unsigned short* row = Yt + (size_t)pc * 512 + qc * 128;
    float acc[8] = {};
    for (int cc = 0; cc < 128; cc += 8) {
        u32x4 v = *(const u32x4*)(row + cc);
        unsigned short e[8];
        *(u32x4*)e = v;
        #pragma unroll
        for (int j = 0; j < 8; j++) {
            float x = bf2f(e[j]);
            int c = qc * 128 + cc + j;
            #pragma unroll
            for (int h = 0; h < 8; h++) acc[h] += wf[h * 512 + c] * x;
        }
    }
    #pragma unroll
    for (int h = 0; h < 8; h++) {
        acc[h] += __shfl_xor(acc[h], 1);
        acc[h] += __shfl_xor(acc[h], 2);
    }
    if (qc == 0 && p < NP) {
        #pragma unroll
        for (int h = 0; h < 8; h++) F2[h * NP + p] = fmaxf(acc[h], 0.f);
    }
}

// down-proj: Fo[h][j] = sum_p F2[h][p] * Wd[j][p] + bd[j]
__global__ __launch_bounds__(256) void k_down(const float* __restrict__ F2,
                                              const float* __restrict__ Wd,
                                              const float* __restrict__ bd,
                                              float* __restrict__ Fo)
{
    int wid = threadIdx.x >> 6, lane = threadIdx.x & 63;
    int j = blockIdx.x * 4 + wid;
    if (j >= PR) return;
    const float* wr = Wd + (size_t)j * NP;
    float acc[8] = {};
    for (int p = lane; p < NP; p += 64) {
        float wv = wr[p];
        #pragma unroll
        for (int h = 0; h < 8; h++) acc[h] += wv * F2[h * NP + p];
    }
    #pragma unroll
    for (int h = 0; h < 8; h++) {
        #pragma unroll
        for (int off = 32; off; off >>= 1) acc[h] += __shfl_down(acc[h], off);
    }
    if (lane == 0) {
        float b = bd[j];
        #pragma unroll
        for (int h = 0; h < 8; h++) Fo[h * PR + j] = acc[h] + b;
    }
}

// ---------------- FFT stages (parallel, twiddle table in global) ----------------

__global__ __launch_bounds__(128) void k_twid(double* __restrict__ ctd, double* __restrict__ snd,
                                              float* __restrict__ ctf, float* __restrict__ stf)
{
    int t = threadIdx.x;
    if (t < 65) {
        double ang = 6.283185307179586476925286766559 * (double)t / 65.0;
        double cv = cos(ang), sv = sin(ang);
        ctd[t] = cv; snd[t] = sv;
        ctf[t] = (float)cv; stf[t] = (float)sv;
    }
}

// stage A: T[y][v] = sum_x A[h][y][x] e^{-2pi i v x/65}  (f64 accum), grid 520 x 64
__global__ __launch_bounds__(64) void k_fftA(const float* __restrict__ A,
                                             const double* __restrict__ ctd,
                                             const double* __restrict__ snd,
                                             float* __restrict__ TrG, float* __restrict__ TiG)
{
    int b = blockIdx.x;
    int h = b / 65, y = b % 65;
    int lane = threadIdx.x;
    __shared__ float rowA[65];
    __shared__ double c65[65], s65[65];
    rowA[lane] = A[h * NP + y * 65 + lane];
    c65[lane] = ctd[lane]; s65[lane] = snd[lane];
    if (lane == 0) {
        rowA[64] = A[h * NP + y * 65 + 64];
        c65[64] = ctd[64]; s65[64] = snd[64];
    }
    __syncthreads();
    int v = lane;
    if (v < 33) {
        double sr = 0.0, si = 0.0;
        for (int x = 0; x < 65; x++) {
            int m = (v * x) % 65;
            double a = (double)rowA[x];
            sr += a * c65[m];
            si -= a * s65[m];
        }
        TrG[(h * 65 + y) * 33 + v] = (float)sr;
        TiG[(h * 65 + y) * 33 + v] = (float)si;
    }
}

// stage B: Af[u][v] = sum_y e^{-2pi i u y/65} T[y][v] (f64), then amp/phase modulation
__global__ __launch_bounds__(128) void k_fftB(const float* __restrict__ TrG,
                                              const float* __restrict__ TiG,
                                              const float* __restrict__ Fa,
                                              const float* __restrict__ Fp,
                                              const double* __restrict__ ctd,
                                              const double* __restrict__ snd,
                                              float* __restrict__ BrG, float* __restrict__ BiG)
{
    int v = blockIdx.x, h = blockIdx.y;
    int t = threadIdx.x;
    __shared__ float TrS[65], TiS[65];
    __shared__ double c65[65], s65[65];
    if (t < 65) {
        TrS[t] = TrG[(h * 65 + t) * 33 + v];
        TiS[t] = TiG[(h * 65 + t) * 33 + v];
        c65[t] = ctd[t]; s65[t] = snd[t];
    }
    __syncthreads();
    int u = t;
    if (u < 65) {
        double sr = 0.0, si = 0.0;
        for (int y = 0; y < 65; y++) {
            int m = (u * y) % 65;
            double c = c65[m], s = s65[m];
            double tr = (double)TrS[y], ti = (double)TiS[y];
            sr += tr * c + ti * s;
            si += ti * c - tr * s;
        }
        float re = (float)sr, im = (float)si;
        float mag = sqrtf(re * re + im * im);
        float ang = atan2f(im, re);
        int o = u * 33 + v;
        float amp = Fa[h * PR + o] * mag;
        float ph  = Fp[h * PR + o] * ang;
        float sn, cn;
        sincosf(ph, &sn, &cn);
        BrG[(h * 65 + u) * 33 + v] = amp * cn;
        BiG[(h * 65 + u) * 33 + v] = amp * sn;
    }
}

// stage C: C[y][v] = sum_u e^{+2pi i u y/65} B[u][v]  (f32)
__global__ __launch_bounds__(128) void k_fftC(const float* __restrict__ BrG,
                                              const float* __restrict__ BiG,
                                              const float* __restrict__ ctf,
                                              const float* __restrict__ stf,
                                              float* __restrict__ CrG, float* __restrict__ CiG)
{
    int v = blockIdx.x, h = blockIdx.y;
    int t = threadIdx.x;
    __shared__ float BrS[65], BiS[65];
    __shared__ float c65[65], s65[65];
    if (t < 65) {
        BrS[t] = BrG[(h * 65 + t) * 33 + v];
        BiS[t] = BiG[(h * 65 + t) * 33 + v];
        c65[t] = ctf[t]; s65[t] = stf[t];
    }
    __syncthreads();
    int y = t;
    if (y < 65) {
        float sr = 0.f, si = 0.f;
        for (int u = 0; u < 65; u++) {
            int m = (u * y) % 65;
            float c = c65[m], s = s65[m];
            float ar = BrS[u], ai = BiS[u];
            sr += ar * c - ai * s;
            si += ai * c + ar * s;
        }
        CrG[(h * 65 + y) * 33 + v] = sr;
        CiG[(h * 65 + y) * 33 + v] = si;
    }
}

// stage D: irfft rows: A2[h][y][x] = (C[y][0] + 2*sum_{v>=1}(Cr cos - Ci sin)) / 4225
__global__ __launch_bounds__(128) void k_fftD(const float* __restrict__ CrG,
                                              const float* __restrict__ CiG,
                                              const float* __restrict__ ctf,
                                              const float* __restrict__ stf,
                                              float* __restrict__ A2)
{
    int y = blockIdx.x, h = blockIdx.y;
    int t = threadIdx.x;
    __shared__ float CrS[33], CiS[33];
    __shared__ float c65[65], s65[65];
    if (t < 33) {
        CrS[t] = CrG[(h * 65 + y) * 33 + t];
        CiS[t] = CiG[(h * 65 + y) * 33 + t];
    }
    if (t < 65) { c65[t] = ctf[t]; s65[t] = stf[t]; }
    __syncthreads();
    int x = t;
    if (x < 65) {
        float s = CrS[0];
        for (int v = 1; v < 33; v++) {
            int m = (v * x) % 65;
            s += 2.f * (CrS[v] * c65[m] - CiS[v] * s65[m]);
        }
        A2[h * NP + y * 65 + x] = s * (1.f / 4225.f);
    }
}

__global__ __launch_bounds__(1024) void k_softmax(const float* __restrict__ A2,
                                                  float* __restrict__ Wsm)
{
    int h = blockIdx.x, tid = threadIdx.x;
    __shared__ float red[1024];
    float mx = -3.0e38f;
    for (int i = tid; i < NP; i += 1024) mx = fmaxf(mx, A2[h * NP + i]);
    red[tid] = mx; __syncthreads();
    for (int s = 512; s; s >>= 1) {
        if (tid < s) red[tid] = fmaxf(red[tid], red[tid + s]);
        __syncthreads();
    }
    mx = red[0]; __syncthreads();
    float sum = 0.f;
    for (int i = tid; i < NP; i += 1024) sum += expf(A2[h * NP + i] - mx);
    red[tid] = sum; __syncthreads();
    for (int s = 512; s; s >>= 1) {
        if (tid < s) red[tid] += red[tid + s];
        __syncthreads();
    }
    float inv = 1.f / red[0];
    for (int i = tid; i < NP; i += 1024) Wsm[h * NP + i] = expf(A2[h * NP + i] - mx) * inv;
}

__global__ __launch_bounds__(256) void k_t(const float* __restrict__ K,
                                           const float* __restrict__ Wsm,
                                           float* __restrict__ t)
{
    int wid = threadIdx.x >> 6, lane = threadIdx.x & 63;
    int c = blockIdx.x * 4 + wid;
    float acc[8] = {};
    for (int p = lane; p < NP; p += 64) {
        float kv = K[(size_t)c * NP + p];
        #pragma unroll
        for (int h = 0; h < 8; h++) acc[h] += kv * Wsm[h * NP + p];
    }
    #pragma unroll
    for (int h = 0; h < 8; h++) {
        #pragma unroll
        for (int off = 32; off; off >>= 1) acc[h] += __shfl_down(acc[h], off);
    }
    if (lane == 0) {
        #pragma unroll
        for (int h = 0; h < 8; h++) t[h * 512 + c] = acc[h];
    }
}

__global__ __launch_bounds__(256) void k_x(const float* __restrict__ t,
                                           const float* __restrict__ Wv,
                                           const float* __restrict__ bv,
                                           float* __restrict__ x)
{
    int wid = threadIdx.x >> 6, lane = threadIdx.x & 63;
    int hd = blockIdx.x * 4 + wid;
    int h = hd >> 9;
    float s = 0.f;
    for (int c = lane; c < 512; c += 64) s += t[h * 512 + c] * Wv[(size_t)hd * 512 + c];
    #pragma unroll
    for (int off = 32; off; off >>= 1) s += __shfl_down(s, off);
    if (lane == 0) x[hd] = s + bv[hd];
}

__global__ __launch_bounds__(256) void k_out(const float* __restrict__ x,
                                             const float* __restrict__ Wo,
                                             const float* __restrict__ bo,
                                             float* __restrict__ out)
{
    int wid = threadIdx.x >> 6, lane = threadIdx.x & 63;
    int j = blockIdx.x * 4 + wid;
    float s = 0.f;
    for (int i = lane; i < 4096; i += 64) s += x[i] * Wo[(size_t)j * 4096 + i];
    #pragma unroll
    for (int off = 32; off; off >>= 1) s += __shfl_down(s, off);
    if (lane == 0) out[j] = s + bo[j];
}

extern "C" void kernel_launch(void* const* d_in, const int* in_sizes, int n_in,
                              void* d_out, int out_size, void* d_ws, size_t ws_size,
                              hipStream_t stream)
{
    (void)in_sizes; (void)n_in; (void)out_size; (void)ws_size;
    const float* Q    = (const float*)d_in[0];
    const float* K    = (const float*)d_in[1];
    const float* Wq   = (const float*)d_in[2];
    const float* bq   = (const float*)d_in[3];
    const float* Wk   = (const float*)d_in[4];
    const float* bk   = (const float*)d_in[5];
    const float* Wv   = (const float*)d_in[6];
    const float* bv   = (const float*)d_in[7];
    const float* Wo   = (const float*)d_in[8];
    const float* bo   = (const float*)d_in[9];
    const float* amp1 = (const float*)d_in[10];
    const float* amp2 = (const float*)d_in[11];
    const float* amp3 = (const float*)d_in[12];
    const float* pha1 = (const float*)d_in[13];
    const float* pha2 = (const float*)d_in[14];
    const float* pha3 = (const float*)d_in[15];
    const float* Wd1  = (const float*)d_in[16];
    const float* bd1  = (const float*)d_in[17];
    const float* Wd2  = (const float*)d_in[18];
    const float* bd2  = (const float*)d_in[19];
    float* out = (float*)d_out;

    char* w = (char*)d_ws;
    auto alloc = [&](size_t bytes) { char* p = w; w += (bytes + 255) & ~(size_t)255; return p; };
    float* qv   = (float*)alloc(4096 * 4);
    float* qkp  = (float*)alloc(16 * 8 * 512 * 4);
    float* qb   = (float*)alloc(64 * 4);
    float* A    = (float*)alloc(8 * NP * 4);
    unsigned short* w1b  = (unsigned short*)alloc((size_t)512 * 512 * 2);
    unsigned short* w2b  = (unsigned short*)alloc((size_t)512 * 4608 * 2);
    unsigned short* f0rb = (unsigned short*)alloc((size_t)NP * 512 * 2);
    unsigned short* f0tb = (unsigned short*)alloc((size_t)NP * 512 * 2);
    unsigned short* ytb  = (unsigned short*)alloc((size_t)NP * 512 * 2);
    float* Ap   = (float*)ytb;   // alias: Ap (32*8*NP floats = 4.33 MB) dead before ytb written
    float* F2   = (float*)alloc(8 * NP * 4);
    float* Fa   = (float*)alloc(8 * PR * 4);
    float* Fp   = (float*)alloc(8 * PR * 4);
    float* A2   = (float*)alloc(8 * NP * 4);
    float* wsm  = (float*)alloc(8 * NP * 4);
    float* tt   = (float*)alloc(4096 * 4);
    float* xx   = (float*)alloc(4096 * 4);
    double* ctd = (double*)alloc(65 * 8);
    double* snd = (double*)alloc(65 * 8);
    float* ctf  = (float*)alloc(65 * 4);
    float* stf  = (float*)alloc(65 * 4);
    float* TrG  = (float*)alloc(8 * PR * 4);
    float* TiG  = (float*)alloc(8 * PR * 4);
    float* BrG  = (float*)alloc(8 * PR * 4);
    float* BiG  = (float*)alloc(8 * PR * 4);
    float* CrG  = (float*)alloc(8 * PR * 4);
    float* CiG  = (float*)alloc(8 * PR * 4);
    // total ~19.7 MB

    k_twid<<<1, 128, 0, stream>>>(ctd, snd, ctf, stf);

    // attention logits path (split-K for parallelism)
    k_q<<<1024, 256, 0, stream>>>(Q, Wq, bq, qv);
    k_qk3<<<dim3(2, 8, 16), 256, 0, stream>>>(qv, Wk, qkp);
    k_qb<<<1, 512, 0, stream>>>(qv, bk, qb);
    k_alogits3<<<dim3(17, 32), 256, 0, stream>>>(qkp, K, Ap);
    k_areduce<<<dim3(17, 8), 256, 0, stream>>>(Ap, qb, A);

    // two filter branches
    for (int br = 0; br < 2; br++) {
        const float* w1 = br ? pha1 : amp1;
        const float* w2 = br ? pha2 : amp2;
        const float* w3 = br ? pha3 : amp3;
        const float* Wd = br ? Wd2 : Wd1;
        const float* bd = br ? bd2 : bd1;
        float* Fo = br ? Fp : Fa;
        k_cast<<<1024, 256, 0, stream>>>(w1, w1b, 512 * 512);
        k_packW2<<<1024, 256, 0, stream>>>(w2, w2b);
        k_conv1T<<<dim3(67, 4), 256, 0, stream>>>(K, w1b, f0rb, f0tb);
        k_conv3T<<<dim3(67, 4), 256, 0, stream>>>(f0tb, w2b, f0rb, ytb);
        k_conv8T<<<67, 256, 0, stream>>>(w3, ytb, F2);
        k_down<<<537, 256, 0, stream>>>(F2, Wd, bd, Fo);
    }

    // FFT modulation (4 parallel stages) + softmax + output path
    k_fftA<<<520, 64, 0, stream>>>(A, ctd, snd, TrG, TiG);
    k_fftB<<<dim3(33, 8), 128, 0, stream>>>(TrG, TiG, Fa, Fp, ctd, snd, BrG, BiG);
    k_fftC<<<dim3(33, 8), 128, 0, stream>>>(BrG, BiG, ctf, stf, CrG, CiG);
    k_fftD<<<dim3(65, 8), 128, 0, stream>>>(CrG, CiG, ctf, stf, A2);
    k_softmax<<<8, 1024, 0, stream>>>(A2, wsm);
    k_t<<<128, 256, 0, stream>>>(K, wsm, tt);
    k_x<<<1024, 256, 0, stream>>>(tt, Wv, bv, xx);
    k_out<<<128, 256, 0, stream>>>(xx, Wo, bo, out);
}

// Round 4
// 267.490 us; speedup vs baseline: 6.5051x; 1.3866x over previous
//
#include <hip/hip_runtime.h>
#include <hip/hip_bf16.h>

#define NP 4225      // 65*65 spatial positions
#define PR 2145      // 65*33 rfft bins

typedef __attribute__((ext_vector_type(8))) short short8;    // 8 bf16 (4 VGPRs)
typedef __attribute__((ext_vector_type(4))) float f32x4;
typedef __attribute__((ext_vector_type(4))) unsigned int u32x4;

__device__ inline float bf2f(unsigned short u) {
    union { unsigned int i; float f; } x; x.i = ((unsigned int)u) << 16; return x.f;
}
__device__ inline unsigned short f2bf(float f) {   // RNE
    union { float f; unsigned int i; } x; x.f = f;
    unsigned int r = x.i + 0x7fff + ((x.i >> 16) & 1);
    return (unsigned short)(r >> 16);
}
// relu on 8 packed bf16 (zero halves with sign bit set)
__device__ inline u32x4 relu8(u32x4 v) {
    #pragma unroll
    for (int i = 0; i < 4; i++) {
        unsigned int s = v[i] & 0x80008000u;
        v[i] &= ~((s >> 15) * 0xFFFFu);
    }
    return v;
}

// ---------------- small projection kernels ----------------

__global__ __launch_bounds__(256) void k_q(const float* __restrict__ Q,
                                           const float* __restrict__ Wq,
                                           const float* __restrict__ bq,
                                           float* __restrict__ qv)
{
    int wid = threadIdx.x >> 6, lane = threadIdx.x & 63;
    int j = blockIdx.x * 4 + wid;
    float s = 0.f;
    for (int i = lane; i < 512; i += 64) s += Q[i] * Wq[j * 512 + i];
    #pragma unroll
    for (int off = 32; off; off >>= 1) s += __shfl_down(s, off);
    if (lane == 0) qv[j] = s + bq[j];
}

// qkp[dz][h][c] = sum over 32 d of q[h, dz*32+d] * Wk[h*512+dz*32+d, c]
__global__ __launch_bounds__(256) void k_qk3(const float* __restrict__ qv,
                                             const float* __restrict__ Wk,
                                             float* __restrict__ qkp)
{
    int c = blockIdx.x * 256 + threadIdx.x;
    int h = blockIdx.y, dz = blockIdx.z;
    __shared__ float qs[32];
    if (threadIdx.x < 32) qs[threadIdx.x] = qv[h * 512 + dz * 32 + threadIdx.x];
    __syncthreads();
    float s = 0.f;
    #pragma unroll 8
    for (int d = 0; d < 32; d++)
        s += qs[d] * Wk[(size_t)(h * 512 + dz * 32 + d) * 512 + c];
    qkp[(dz * 8 + h) * 512 + c] = s;
}

__global__ __launch_bounds__(512) void k_qb(const float* __restrict__ q,
                                            const float* __restrict__ bk,
                                            float* __restrict__ qb)
{
    int h = threadIdx.x >> 6, lane = threadIdx.x & 63;
    float s = 0.f;
    for (int d = lane; d < 512; d += 64) s += q[h * 512 + d] * bk[h * 512 + d];
    #pragma unroll
    for (int off = 32; off; off >>= 1) s += __shfl_down(s, off);
    if (lane == 0) qb[h] = s;
}

// Ap[cz][h][p] partials: sum over 16 c of qk[h,c]*K[c,p]
__global__ __launch_bounds__(256) void k_alogits3(const float* __restrict__ qkp,
                                                  const float* __restrict__ K,
                                                  float* __restrict__ Ap)
{
    __shared__ float sqk[8][16];
    int tid = threadIdx.x;
    int cz = blockIdx.y;
    if (tid < 128) {
        int hh = tid >> 4, cc = tid & 15;
        float s = 0.f;
        #pragma unroll
        for (int dz = 0; dz < 16; dz++) s += qkp[(dz * 8 + hh) * 512 + cz * 16 + cc];
        sqk[hh][cc] = s;
    }
    __syncthreads();
    int p = blockIdx.x * 256 + tid;
    bool ok = p < NP;
    float acc[8] = {};
    #pragma unroll
    for (int cc = 0; cc < 16; cc++) {
        float kv = ok ? K[(size_t)(cz * 16 + cc) * NP + p] : 0.f;
        #pragma unroll
        for (int h = 0; h < 8; h++) acc[h] += sqk[h][cc] * kv;
    }
    if (ok) {
        #pragma unroll
        for (int h = 0; h < 8; h++) Ap[(size_t)(cz * 8 + h) * NP + p] = acc[h];
    }
}

// A[h][p] = (sum_cz Ap[cz][h][p] + qb[h]) / sqrt(512)
__global__ __launch_bounds__(256) void k_areduce(const float* __restrict__ Ap,
                                                 const float* __restrict__ qb,
                                                 float* __restrict__ A)
{
    int p = blockIdx.x * 256 + threadIdx.x;
    int h = blockIdx.y;
    if (p >= NP) return;
    float s = 0.f;
    #pragma unroll 8
    for (int cz = 0; cz < 32; cz++) s += Ap[(size_t)(cz * 8 + h) * NP + p];
    const float sc = 0.04419417382415922f;
    A[h * NP + p] = (s + qb[h]) * sc;
}

// ---------------- weight prep (both branches per dispatch) ----------------

__global__ __launch_bounds__(256) void k_cast2(const float* __restrict__ a,
                                               const float* __restrict__ b,
                                               unsigned short* __restrict__ o)
{
    int i = blockIdx.x * 256 + threadIdx.x;   // < 262144
    int br = blockIdx.y;
    const float* src = br ? b : a;
    o[(size_t)br * 262144 + i] = f2bf(src[i]);
}

// (m, c, 3, 3) fp32 -> w2b[br][m][tap*512 + c] bf16
__global__ __launch_bounds__(256) void k_packW2(const float* __restrict__ a,
                                                const float* __restrict__ b,
                                                unsigned short* __restrict__ o)
{
    int i = blockIdx.x * 256 + threadIdx.x;   // over 512*512
    int br = blockIdx.y;
    int m = i >> 9, c = i & 511;
    const float* src = (br ? b : a) + (size_t)i * 9;
    unsigned short* dst = o + (size_t)br * 512 * 4608;
    #pragma unroll
    for (int t = 0; t < 9; t++) dst[(size_t)m * 4608 + t * 512 + c] = f2bf(src[t]);
}

// ---------------- MFMA conv kernels ----------------
// GEMM-T: C[p][m] = sum_k A[p][k] * B[m][k]; 64(p) x 128(m) tile, 4 waves (2x2),
// wave tile 32x64 = 2x4 frags of 16x16, K-chunk 64 (2 mfma k-steps). z = branch.

// conv1x1: A = K^T (fp32->bf16 LDS transpose), B = w1b[br]. Writes raw bf16 f0b[br].
__global__ __launch_bounds__(256) void k_conv1T(const float* __restrict__ K,
                                                const unsigned short* __restrict__ w1b2,
                                                unsigned short* __restrict__ f0b2)
{
    __shared__ unsigned short As[2][64 * 64];
    __shared__ unsigned short Bs[2][128 * 64];
    int tid = threadIdx.x;
    int br = blockIdx.z;
    int bm = blockIdx.x * 64;       // p tile
    int bn = blockIdx.y * 128;      // m tile
    const unsigned short* w1 = w1b2 + (size_t)br * 262144;
    unsigned short* f0 = f0b2 + (size_t)br * NP * 512;
    int lane = tid & 63;
    int w = tid >> 6;
    int wp = (w >> 1) * 32, wm = (w & 1) * 64;
    int rb = tid >> 1, hb = tid & 1;          // B staging map
    int ct = tid >> 4, p4 = (tid & 15) * 4;   // A staging map

    f32x4 acc[2][4];
    #pragma unroll
    for (int i = 0; i < 2; i++)
        #pragma unroll
        for (int j = 0; j < 4; j++) acc[i][j] = (f32x4){0.f, 0.f, 0.f, 0.f};

    float areg[16];
    u32x4 breg[4];

    auto loadRegs = [&](int kc) {
        int c0 = kc * 64;
        #pragma unroll
        for (int pass = 0; pass < 4; pass++) {
            int cl = pass * 16 + ct;
            const float* src = K + (size_t)(c0 + cl) * NP + bm + p4;
            #pragma unroll
            for (int j = 0; j < 4; j++)
                areg[pass * 4 + j] = (bm + p4 + j < NP) ? src[j] : 0.f;
        }
        const unsigned short* brow = w1 + (size_t)(bn + rb) * 512 + c0 + hb * 32;
        #pragma unroll
        for (int j = 0; j < 4; j++) breg[j] = *(const u32x4*)(brow + j * 8);
    };
    auto writeS = [&](int buf) {
        #pragma unroll
        for (int pass = 0; pass < 4; pass++) {
            int cl = pass * 16 + ct;
            #pragma unroll
            for (int j = 0; j < 4; j++) {
                int row = p4 + j;
                int byte = (row * 128 + cl * 2) ^ ((row & 7) << 4);
                *(unsigned short*)((char*)As[buf] + byte) = f2bf(areg[pass * 4 + j]);
            }
        }
        int bb = rb * 128 + hb * 64;
        #pragma unroll
        for (int j = 0; j < 4; j++)
            *(u32x4*)((char*)Bs[buf] + ((bb + j * 16) ^ ((rb & 7) << 4))) = breg[j];
    };

    loadRegs(0);
    writeS(0);
    __syncthreads();
    for (int kc = 0; kc < 8; kc++) {
        if (kc < 7) loadRegs(kc + 1);
        int buf = kc & 1;
        #pragma unroll
        for (int ks = 0; ks < 2; ks++) {
            short8 af[2], bfr[4];
            #pragma unroll
            for (int fi = 0; fi < 2; fi++) {
                int row = wp + fi * 16 + (lane & 15);
                int byte = row * 128 + ((ks * 64 + ((lane >> 4) * 16)) ^ ((row & 7) << 4));
                af[fi] = *(const short8*)((char*)As[buf] + byte);
            }
            #pragma unroll
            for (int fj = 0; fj < 4; fj++) {
                int n = wm + fj * 16 + (lane & 15);
                int byte = n * 128 + ((ks * 64 + ((lane >> 4) * 16)) ^ ((n & 7) << 4));
                bfr[fj] = *(const short8*)((char*)Bs[buf] + byte);
            }
            #pragma unroll
            for (int fi = 0; fi < 2; fi++)
                #pragma unroll
                for (int fj = 0; fj < 4; fj++)
                    acc[fi][fj] = __builtin_amdgcn_mfma_f32_16x16x32_bf16(af[fi], bfr[fj], acc[fi][fj], 0, 0, 0);
        }
        if (kc < 7) writeS((kc + 1) & 1);
        __syncthreads();
    }
    #pragma unroll
    for (int fi = 0; fi < 2; fi++)
        #pragma unroll
        for (int r = 0; r < 4; r++) {
            int p = bm + wp + fi * 16 + (lane >> 4) * 4 + r;
            if (p >= NP) continue;
            #pragma unroll
            for (int fj = 0; fj < 4; fj++) {
                int m = bn + wm + fj * 16 + (lane & 15);
                f0[(size_t)p * 512 + m] = f2bf(acc[fi][fj][r]);
            }
        }
}

// conv3x3 + residual + relu + fused conv8 partial reduction.
// Loop order: kc outer, tap inner (A halo stays L1-resident per kc).
__global__ __launch_bounds__(256) void k_conv3T(const unsigned short* __restrict__ f0b2,
                                                const unsigned short* __restrict__ w2b2,
                                                const float* __restrict__ amp3,
                                                const float* __restrict__ pha3,
                                                float* __restrict__ F2p)
{
    __shared__ unsigned short As[2][64 * 64];
    __shared__ unsigned short Bs[2][128 * 64];
    __shared__ float w3s[8 * 128];
    int tid = threadIdx.x;
    int br = blockIdx.z;
    int bm = blockIdx.x * 64;
    int bn = blockIdx.y * 128;
    const unsigned short* f0 = f0b2 + (size_t)br * NP * 512;
    const unsigned short* w2 = w2b2 + (size_t)br * 512 * 4608;
    const float* w3 = br ? pha3 : amp3;
    for (int i = tid; i < 1024; i += 256) {
        int h = i >> 7, c = i & 127;
        w3s[i] = w3[h * 512 + bn + c];
    }
    int lane = tid & 63;
    int w = tid >> 6;
    int wp = (w >> 1) * 32, wm = (w & 1) * 64;
    int ra = tid >> 2, sa = tid & 3;   // A staging: row, 16-elem segment
    int rb = tid >> 1, hb = tid & 1;   // B staging
    int pA = bm + ra;
    int py = pA / 65, px = pA - py * 65;

    f32x4 acc[2][4];
    #pragma unroll
    for (int i = 0; i < 2; i++)
        #pragma unroll
        for (int j = 0; j < 4; j++) acc[i][j] = (f32x4){0.f, 0.f, 0.f, 0.f};

    u32x4 areg0, areg1, breg[4];

    auto loadRegs = [&](int it) {
        int kc = it / 9, tap = it - kc * 9;    // tap inner: halo L1-resident per kc
        int ky = tap / 3 - 1, kx = tap % 3 - 1;
        int sy = py + ky, sx = px + kx;
        bool valid = (pA < NP) && sy >= 0 && sy < 65 && sx >= 0 && sx < 65;
        int srow = valid ? (pA + ky * 65 + kx) : 0;
        const unsigned short* arow = f0 + (size_t)srow * 512 + kc * 64 + sa * 16;
        u32x4 a0 = relu8(*(const u32x4*)arow);
        u32x4 a1 = relu8(*(const u32x4*)(arow + 8));
        areg0 = valid ? a0 : (u32x4){0, 0, 0, 0};
        areg1 = valid ? a1 : (u32x4){0, 0, 0, 0};
        const unsigned short* brow = w2 + tap * 512 + (size_t)(bn + rb) * 4608 + kc * 64 + hb * 32;
        #pragma unroll
        for (int j = 0; j < 4; j++) breg[j] = *(const u32x4*)(brow + j * 8);
    };
    auto writeS = [&](int buf) {
        int ab = ra * 128 + sa * 32;
        *(u32x4*)((char*)As[buf] + ((ab) ^ ((ra & 7) << 4)))      = areg0;
        *(u32x4*)((char*)As[buf] + ((ab + 16) ^ ((ra & 7) << 4))) = areg1;
        int bb = rb * 128 + hb * 64;
        #pragma unroll
        for (int j = 0; j < 4; j++)
            *(u32x4*)((char*)Bs[buf] + ((bb + j * 16) ^ ((rb & 7) << 4))) = breg[j];
    };

    loadRegs(0);
    writeS(0);
    __syncthreads();
    for (int it = 0; it < 72; it++) {
        if (it < 71) loadRegs(it + 1);
        int buf = it & 1;
        #pragma unroll
        for (int ks = 0; ks < 2; ks++) {
            short8 af[2], bfr[4];
            #pragma unroll
            for (int fi = 0; fi < 2; fi++) {
                int row = wp + fi * 16 + (lane & 15);
                int byte = row * 128 + ((ks * 64 + ((lane >> 4) * 16)) ^ ((row & 7) << 4));
                af[fi] = *(const short8*)((char*)As[buf] + byte);
            }
            #pragma unroll
            for (int fj = 0; fj < 4; fj++) {
                int n = wm + fj * 16 + (lane & 15);
                int byte = n * 128 + ((ks * 64 + ((lane >> 4) * 16)) ^ ((n & 7) << 4));
                bfr[fj] = *(const short8*)((char*)Bs[buf] + byte);
            }
            #pragma unroll
            for (int fi = 0; fi < 2; fi++)
                #pragma unroll
                for (int fj = 0; fj < 4; fj++)
                    acc[fi][fj] = __builtin_amdgcn_mfma_f32_16x16x32_bf16(af[fi], bfr[fj], acc[fi][fj], 0, 0, 0);
        }
        if (it < 71) writeS((it + 1) & 1);
        __syncthreads();
    }
    // epilogue: v = relu(acc + residual) -> LDS (swizzled bf16 tile in Bs[0])
    #pragma unroll
    for (int fi = 0; fi < 2; fi++)
        #pragma unroll
        for (int r = 0; r < 4; r++) {
            int row = wp + fi * 16 + (lane >> 4) * 4 + r;
            int p = bm + row;
            #pragma unroll
            for (int fj = 0; fj < 4; fj++) {
                int mcol = wm + fj * 16 + (lane & 15);
                float v = 0.f;
                if (p < NP)
                    v = fmaxf(acc[fi][fj][r] + bf2f(f0[(size_t)p * 512 + bn + mcol]), 0.f);
                int byte = (row * 256 + mcol * 2) ^ ((row & 7) << 4);
                *(unsigned short*)((char*)Bs[0] + byte) = f2bf(v);
            }
        }
    __syncthreads();
    // fused conv8: partial F2 over this block's 128 channels
    int pl = tid >> 2, qc = tid & 3;
    float a8[8] = {};
    #pragma unroll 4
    for (int jj = 0; jj < 16; jj++) {
        int c = qc * 32 + jj * 2;
        int byte = (pl * 256 + c * 2) ^ ((pl & 7) << 4);
        unsigned int u = *(const unsigned int*)((char*)Bs[0] + byte);
        float v0 = bf2f((unsigned short)(u & 0xFFFF));
        float v1 = bf2f((unsigned short)(u >> 16));
        #pragma unroll
        for (int h = 0; h < 8; h++)
            a8[h] += w3s[h * 128 + c] * v0 + w3s[h * 128 + c + 1] * v1;
    }
    #pragma unroll
    for (int h = 0; h < 8; h++) {
        a8[h] += __shfl_xor(a8[h], 1);
        a8[h] += __shfl_xor(a8[h], 2);
    }
    int p = bm + pl;
    if (qc == 0 && p < NP) {
        float* dst = F2p + (size_t)(br * 4 + blockIdx.y) * 8 * NP;
        #pragma unroll
        for (int h = 0; h < 8; h++) dst[h * NP + p] = a8[h];
    }
}

// F2[br][h][p] = relu(sum over 4 bn partials)
__global__ __launch_bounds__(256) void k_f2red(const float* __restrict__ F2p,
                                               float* __restrict__ F2)
{
    int p = blockIdx.x * 256 + threadIdx.x;
    int h = blockIdx.y, br = blockIdx.z;
    if (p >= NP) return;
    float s = 0.f;
    #pragma unroll
    for (int bn = 0; bn < 4; bn++) s += F2p[(size_t)((br * 4 + bn) * 8 + h) * NP + p];
    F2[(size_t)(br * 8 + h) * NP + p] = fmaxf(s, 0.f);
}

// down-proj both branches: Fo[h][j] = sum_p F2[br][h][p] * Wd[j][p] + bd[j]
__global__ __launch_bounds__(256) void k_down(const float* __restrict__ F2,
                                              const float* __restrict__ Wd1,
                                              const float* __restrict__ bd1,
                                              const float* __restrict__ Wd2,
                                              const float* __restrict__ bd2,
                                              float* __restrict__ Fa,
                                              float* __restrict__ Fp)
{
    int wid = threadIdx.x >> 6, lane = threadIdx.x & 63;
    int j = blockIdx.x * 4 + wid;
    if (j >= PR) return;
    int br = blockIdx.y;
    const float* Wd = br ? Wd2 : Wd1;
    const float* bd = br ? bd2 : bd1;
    const float* F2b = F2 + (size_t)br * 8 * NP;
    float* Fo = br ? Fp : Fa;
    const float* wr = Wd + (size_t)j * NP;
    float acc[8] = {};
    for (int p = lane; p < NP; p += 64) {
        float wv = wr[p];
        #pragma unroll
        for (int h = 0; h < 8; h++) acc[h] += wv * F2b[h * NP + p];
    }
    #pragma unroll
    for (int h = 0; h < 8; h++) {
        #pragma unroll
        for (int off = 32; off; off >>= 1) acc[h] += __shfl_down(acc[h], off);
    }
    if (lane == 0) {
        float b = bd[j];
        #pragma unroll
        for (int h = 0; h < 8; h++) Fo[h * PR + j] = acc[h] + b;
    }
}

// ---------------- FFT stages ----------------

__global__ __launch_bounds__(128) void k_twid(double* __restrict__ ctd, double* __restrict__ snd,
                                              float* __restrict__ ctf, float* __restrict__ stf)
{
    int t = threadIdx.x;
    if (t < 65) {
        double ang = 6.283185307179586476925286766559 * (double)t / 65.0;
        double cv = cos(ang), sv = sin(ang);
        ctd[t] = cv; snd[t] = sv;
        ctf[t] = (float)cv; stf[t] = (float)sv;
    }
}

// stage A: T[y][v] = sum_x A[h][y][x] e^{-2pi i v x/65}  (f64 accum)
__global__ __launch_bounds__(64) void k_fftA(const float* __restrict__ A,
                                             const double* __restrict__ ctd,
                                             const double* __restrict__ snd,
                                             float* __restrict__ TrG, float* __restrict__ TiG)
{
    int b = blockIdx.x;
    int h = b / 65, y = b % 65;
    int lane = threadIdx.x;
    __shared__ float rowA[65];
    __shared__ double c65[65], s65[65];
    rowA[lane] = A[h * NP + y * 65 + lane];
    c65[lane] = ctd[lane]; s65[lane] = snd[lane];
    if (lane == 0) {
        rowA[64] = A[h * NP + y * 65 + 64];
        c65[64] = ctd[64]; s65[64] = snd[64];
    }
    __syncthreads();
    int v = lane;
    if (v < 33) {
        double sr = 0.0, si = 0.0;
        for (int x = 0; x < 65; x++) {
            int m = (v * x) % 65;
            double a = (double)rowA[x];
            sr += a * c65[m];
            si -= a * s65[m];
        }
        TrG[(h * 65 + y) * 33 + v] = (float)sr;
        TiG[(h * 65 + y) * 33 + v] = (float)si;
    }
}

// stage B: col-DFT (f64) + amp/phase modulation
__global__ __launch_bounds__(128) void k_fftB(const float* __restrict__ TrG,
                                              const float* __restrict__ TiG,
                                              const float* __restrict__ Fa,
                                              const float* __restrict__ Fp,
                                              const double* __restrict__ ctd,
                                              const double* __restrict__ snd,
                                              float* __restrict__ BrG, float* __restrict__ BiG)
{
    int v = blockIdx.x, h = blockIdx.y;
    int t = threadIdx.x;
    __shared__ float TrS[65], TiS[65];
    __shared__ double c65[65], s65[65];
    if (t < 65) {
        TrS[t] = TrG[(h * 65 + t) * 33 + v];
        TiS[t] = TiG[(h * 65 + t) * 33 + v];
        c65[t] = ctd[t]; s65[t] = snd[t];
    }
    __syncthreads();
    int u = t;
    if (u < 65) {
        double sr = 0.0, si = 0.0;
        for (int y = 0; y < 65; y++) {
            int m = (u * y) % 65;
            double c = c65[m], s = s65[m];
            double tr = (double)TrS[y], ti = (double)TiS[y];
            sr += tr * c + ti * s;
            si += ti * c - tr * s;
        }
        float re = (float)sr, im = (float)si;
        float mag = sqrtf(re * re + im * im);
        float ang = atan2f(im, re);
        int o = u * 33 + v;
        float amp = Fa[h * PR + o] * mag;
        float ph  = Fp[h * PR + o] * ang;
        float sn, cn;
        sincosf(ph, &sn, &cn);
        BrG[(h * 65 + u) * 33 + v] = amp * cn;
        BiG[(h * 65 + u) * 33 + v] = amp * sn;
    }
}

// stage C: inverse col-DFT (f32)
__global__ __launch_bounds__(128) void k_fftC(const float* __restrict__ BrG,
                                              const float* __restrict__ BiG,
                                              const float* __restrict__ ctf,
                                              const float* __restrict__ stf,
                                              float* __restrict__ CrG, float* __restrict__ CiG)
{
    int v = blockIdx.x, h = blockIdx.y;
    int t = threadIdx.x;
    __shared__ float BrS[65], BiS[65];
    __shared__ float c65[65], s65[65];
    if (t < 65) {
        BrS[t] = BrG[(h * 65 + t) * 33 + v];
        BiS[t] = BiG[(h * 65 + t) * 33 + v];
        c65[t] = ctf[t]; s65[t] = stf[t];
    }
    __syncthreads();
    int y = t;
    if (y < 65) {
        float sr = 0.f, si = 0.f;
        for (int u = 0; u < 65; u++) {
            int m = (u * y) % 65;
            float c = c65[m], s = s65[m];
            float ar = BrS[u], ai = BiS[u];
            sr += ar * c - ai * s;
            si += ai * c + ar * s;
        }
        CrG[(h * 65 + y) * 33 + v] = sr;
        CiG[(h * 65 + y) * 33 + v] = si;
    }
}

// stage D: irfft rows
__global__ __launch_bounds__(128) void k_fftD(const float* __restrict__ CrG,
                                              const float* __restrict__ CiG,
                                              const float* __restrict__ ctf,
                                              const float* __restrict__ stf,
                                              float* __restrict__ A2)
{
    int y = blockIdx.x, h = blockIdx.y;
    int t = threadIdx.x;
    __shared__ float CrS[33], CiS[33];
    __shared__ float c65[65], s65[65];
    if (t < 33) {
        CrS[t] = CrG[(h * 65 + y) * 33 + t];
        CiS[t] = CiG[(h * 65 + y) * 33 + t];
    }
    if (t < 65) { c65[t] = ctf[t]; s65[t] = stf[t]; }
    __syncthreads();
    int x = t;
    if (x < 65) {
        float s = CrS[0];
        for (int v = 1; v < 33; v++) {
            int m = (v * x) % 65;
            s += 2.f * (CrS[v] * c65[m] - CiS[v] * s65[m]);
        }
        A2[h * NP + y * 65 + x] = s * (1.f / 4225.f);
    }
}

__global__ __launch_bounds__(1024) void k_softmax(const float* __restrict__ A2,
                                                  float* __restrict__ Wsm)
{
    int h = blockIdx.x, tid = threadIdx.x;
    __shared__ float red[1024];
    float mx = -3.0e38f;
    for (int i = tid; i < NP; i += 1024) mx = fmaxf(mx, A2[h * NP + i]);
    red[tid] = mx; __syncthreads();
    for (int s = 512; s; s >>= 1) {
        if (tid < s) red[tid] = fmaxf(red[tid], red[tid + s]);
        __syncthreads();
    }
    mx = red[0]; __syncthreads();
    float sum = 0.f;
    for (int i = tid; i < NP; i += 1024) sum += expf(A2[h * NP + i] - mx);
    red[tid] = sum; __syncthreads();
    for (int s = 512; s; s >>= 1) {
        if (tid < s) red[tid] += red[tid + s];
        __syncthreads();
    }
    float inv = 1.f / red[0];
    for (int i = tid; i < NP; i += 1024) Wsm[h * NP + i] = expf(A2[h * NP + i] - mx) * inv;
}

__global__ __launch_bounds__(256) void k_t(const float* __restrict__ K,
                                           const float* __restrict__ Wsm,
                                           float* __restrict__ t)
{
    int wid = threadIdx.x >> 6, lane = threadIdx.x & 63;
    int c = blockIdx.x * 4 + wid;
    float acc[8] = {};
    for (int p = lane; p < NP; p += 64) {
        float kv = K[(size_t)c * NP + p];
        #pragma unroll
        for (int h = 0; h < 8; h++) acc[h] += kv * Wsm[h * NP + p];
    }
    #pragma unroll
    for (int h = 0; h < 8; h++) {
        #pragma unroll
        for (int off = 32; off; off >>= 1) acc[h] += __shfl_down(acc[h], off);
    }
    if (lane == 0) {
        #pragma unroll
        for (int h = 0; h < 8; h++) t[h * 512 + c] = acc[h];
    }
}

__global__ __launch_bounds__(256) void k_x(const float* __restrict__ t,
                                           const float* __restrict__ Wv,
                                           const float* __restrict__ bv,
                                           float* __restrict__ x)
{
    int wid = threadIdx.x >> 6, lane = threadIdx.x & 63;
    int hd = blockIdx.x * 4 + wid;
    int h = hd >> 9;
    float s = 0.f;
    for (int c = lane; c < 512; c += 64) s += t[h * 512 + c] * Wv[(size_t)hd * 512 + c];
    #pragma unroll
    for (int off = 32; off; off >>= 1) s += __shfl_down(s, off);
    if (lane == 0) x[hd] = s + bv[hd];
}

__global__ __launch_bounds__(256) void k_out(const float* __restrict__ x,
                                             const float* __restrict__ Wo,
                                             const float* __restrict__ bo,
                                             float* __restrict__ out)
{
    int wid = threadIdx.x >> 6, lane = threadIdx.x & 63;
    int j = blockIdx.x * 4 + wid;
    float s = 0.f;
    for (int i = lane; i < 4096; i += 64) s += x[i] * Wo[(size_t)j * 4096 + i];
    #pragma unroll
    for (int off = 32; off; off >>= 1) s += __shfl_down(s, off);
    if (lane == 0) out[j] = s + bo[j];
}

extern "C" void kernel_launch(void* const* d_in, const int* in_sizes, int n_in,
                              void* d_out, int out_size, void* d_ws, size_t ws_size,
                              hipStream_t stream)
{
    (void)in_sizes; (void)n_in; (void)out_size; (void)ws_size;
    const float* Q    = (const float*)d_in[0];
    const float* K    = (const float*)d_in[1];
    const float* Wq   = (const float*)d_in[2];
    const float* bq   = (const float*)d_in[3];
    const float* Wk   = (const float*)d_in[4];
    const float* bk   = (const float*)d_in[5];
    const float* Wv   = (const float*)d_in[6];
    const float* bv   = (const float*)d_in[7];
    const float* Wo   = (const float*)d_in[8];
    const float* bo   = (const float*)d_in[9];
    const float* amp1 = (const float*)d_in[10];
    const float* amp2 = (const float*)d_in[11];
    const float* amp3 = (const float*)d_in[12];
    const float* pha1 = (const float*)d_in[13];
    const float* pha2 = (const float*)d_in[14];
    const float* pha3 = (const float*)d_in[15];
    const float* Wd1  = (const float*)d_in[16];
    const float* bd1  = (const float*)d_in[17];
    const float* Wd2  = (const float*)d_in[18];
    const float* bd2  = (const float*)d_in[19];
    float* out = (float*)d_out;

    char* w = (char*)d_ws;
    auto alloc = [&](size_t bytes) { char* p = w; w += (bytes + 255) & ~(size_t)255; return p; };
    float* qv   = (float*)alloc(4096 * 4);
    float* qkp  = (float*)alloc(16 * 8 * 512 * 4);
    float* qb   = (float*)alloc(64 * 4);
    float* A    = (float*)alloc(8 * NP * 4);
    unsigned short* w1b2 = (unsigned short*)alloc((size_t)2 * 512 * 512 * 2);
    unsigned short* w2b2 = (unsigned short*)alloc((size_t)2 * 512 * 4608 * 2);
    unsigned short* f0b2 = (unsigned short*)alloc((size_t)2 * NP * 512 * 2);
    float* F2p  = (float*)alloc((size_t)2 * 4 * 8 * NP * 4);
    float* F2   = (float*)alloc((size_t)2 * 8 * NP * 4);
    float* Fa   = (float*)alloc(8 * PR * 4);
    float* Fp   = (float*)alloc(8 * PR * 4);
    double* ctd = (double*)alloc(65 * 8);
    double* snd = (double*)alloc(65 * 8);
    float* ctf  = (float*)alloc(65 * 4);
    float* stf  = (float*)alloc(65 * 4);
    // Ap aliases w2b2 (Ap dead before k_packW2 writes w2b2)
    float* Ap   = (float*)w2b2;
    // post-conv small buffers alias f0b2 (dead after k_conv3T)
    {
        char* s2 = (char*)f0b2;
        auto alias = [&](size_t bytes) { char* p = s2; s2 += (bytes + 255) & ~(size_t)255; return p; };
        float* A2  = (float*)alias(8 * NP * 4);
        float* wsm = (float*)alias(8 * NP * 4);
        float* tt  = (float*)alias(4096 * 4);
        float* xx  = (float*)alias(4096 * 4);
        float* TrG = (float*)alias(8 * PR * 4);
        float* TiG = (float*)alias(8 * PR * 4);
        float* BrG = (float*)alias(8 * PR * 4);
        float* BiG = (float*)alias(8 * PR * 4);
        float* CrG = (float*)alias(8 * PR * 4);
        float* CiG = (float*)alias(8 * PR * 4);

        k_twid<<<1, 128, 0, stream>>>(ctd, snd, ctf, stf);

        // attention logits path (split-K; Ap lives in w2b2 region until areduce)
        k_q<<<1024, 256, 0, stream>>>(Q, Wq, bq, qv);
        k_qk3<<<dim3(2, 8, 16), 256, 0, stream>>>(qv, Wk, qkp);
        k_qb<<<1, 512, 0, stream>>>(qv, bk, qb);
        k_alogits3<<<dim3(17, 32), 256, 0, stream>>>(qkp, K, Ap);
        k_areduce<<<dim3(17, 8), 256, 0, stream>>>(Ap, qb, A);

        // weight prep (overwrites Ap region — after areduce)
        k_cast2<<<dim3(1024, 2), 256, 0, stream>>>(amp1, pha1, w1b2);
        k_packW2<<<dim3(1024, 2), 256, 0, stream>>>(amp2, pha2, w2b2);

        // conv branches, merged (z = branch)
        k_conv1T<<<dim3(67, 4, 2), 256, 0, stream>>>(K, w1b2, f0b2);
        k_conv3T<<<dim3(67, 4, 2), 256, 0, stream>>>(f0b2, w2b2, amp3, pha3, F2p);
        k_f2red<<<dim3(17, 8, 2), 256, 0, stream>>>(F2p, F2);
        k_down<<<dim3(537, 2), 256, 0, stream>>>(F2, Wd1, bd1, Wd2, bd2, Fa, Fp);

        // FFT modulation + softmax + output (f0b2 region reused as scratch)
        k_fftA<<<520, 64, 0, stream>>>(A, ctd, snd, TrG, TiG);
        k_fftB<<<dim3(33, 8), 128, 0, stream>>>(TrG, TiG, Fa, Fp, ctd, snd, BrG, BiG);
        k_fftC<<<dim3(33, 8), 128, 0, stream>>>(BrG, BiG, ctf, stf, CrG, CiG);
        k_fftD<<<dim3(65, 8), 128, 0, stream>>>(CrG, CiG, ctf, stf, A2);
        k_softmax<<<8, 1024, 0, stream>>>(A2, wsm);
        k_t<<<128, 256, 0, stream>>>(K, wsm, tt);
        k_x<<<1024, 256, 0, stream>>>(tt, Wv, bv, xx);
        k_out<<<128, 256, 0, stream>>>(xx, Wo, bo, out);
    }
}

// Round 5
// 264.298 us; speedup vs baseline: 6.5837x; 1.0121x over previous
//
#include <hip/hip_runtime.h>
#include <hip/hip_bf16.h>

#define NP 4225      // 65*65 spatial positions
#define PR 2145      // 65*33 rfft bins

typedef __attribute__((ext_vector_type(8))) short short8;    // 8 bf16 (4 VGPRs)
typedef __attribute__((ext_vector_type(4))) float f32x4;
typedef __attribute__((ext_vector_type(4))) unsigned int u32x4;

__device__ inline float bf2f(unsigned short u) {
    union { unsigned int i; float f; } x; x.i = ((unsigned int)u) << 16; return x.f;
}
__device__ inline unsigned short f2bf(float f) {   // RNE
    union { float f; unsigned int i; } x; x.f = f;
    unsigned int r = x.i + 0x7fff + ((x.i >> 16) & 1);
    return (unsigned short)(r >> 16);
}
// relu on 8 packed bf16 (zero halves with sign bit set)
__device__ inline u32x4 relu8(u32x4 v) {
    #pragma unroll
    for (int i = 0; i < 4; i++) {
        unsigned int s = v[i] & 0x80008000u;
        v[i] &= ~((s >> 15) * 0xFFFFu);
    }
    return v;
}

// ---------------- small projection kernels ----------------

__global__ __launch_bounds__(256) void k_q(const float* __restrict__ Q,
                                           const float* __restrict__ Wq,
                                           const float* __restrict__ bq,
                                           float* __restrict__ qv)
{
    int wid = threadIdx.x >> 6, lane = threadIdx.x & 63;
    int j = blockIdx.x * 4 + wid;
    float s = 0.f;
    for (int i = lane; i < 512; i += 64) s += Q[i] * Wq[j * 512 + i];
    #pragma unroll
    for (int off = 32; off; off >>= 1) s += __shfl_down(s, off);
    if (lane == 0) qv[j] = s + bq[j];
}

// qkp[dz][h][c] = sum over 32 d of q[h, dz*32+d] * Wk[h*512+dz*32+d, c]
__global__ __launch_bounds__(256) void k_qk3(const float* __restrict__ qv,
                                             const float* __restrict__ Wk,
                                             float* __restrict__ qkp)
{
    int c = blockIdx.x * 256 + threadIdx.x;
    int h = blockIdx.y, dz = blockIdx.z;
    __shared__ float qs[32];
    if (threadIdx.x < 32) qs[threadIdx.x] = qv[h * 512 + dz * 32 + threadIdx.x];
    __syncthreads();
    float s = 0.f;
    #pragma unroll 8
    for (int d = 0; d < 32; d++)
        s += qs[d] * Wk[(size_t)(h * 512 + dz * 32 + d) * 512 + c];
    qkp[(dz * 8 + h) * 512 + c] = s;
}

__global__ __launch_bounds__(512) void k_qb(const float* __restrict__ q,
                                            const float* __restrict__ bk,
                                            float* __restrict__ qb)
{
    int h = threadIdx.x >> 6, lane = threadIdx.x & 63;
    float s = 0.f;
    for (int d = lane; d < 512; d += 64) s += q[h * 512 + d] * bk[h * 512 + d];
    #pragma unroll
    for (int off = 32; off; off >>= 1) s += __shfl_down(s, off);
    if (lane == 0) qb[h] = s;
}

// Ap[cz][h][p] partials: sum over 16 c of qk[h,c]*K[c,p]
__global__ __launch_bounds__(256) void k_alogits3(const float* __restrict__ qkp,
                                                  const float* __restrict__ K,
                                                  float* __restrict__ Ap)
{
    __shared__ float sqk[8][16];
    int tid = threadIdx.x;
    int cz = blockIdx.y;
    if (tid < 128) {
        int hh = tid >> 4, cc = tid & 15;
        float s = 0.f;
        #pragma unroll
        for (int dz = 0; dz < 16; dz++) s += qkp[(dz * 8 + hh) * 512 + cz * 16 + cc];
        sqk[hh][cc] = s;
    }
    __syncthreads();
    int p = blockIdx.x * 256 + tid;
    bool ok = p < NP;
    float acc[8] = {};
    #pragma unroll
    for (int cc = 0; cc < 16; cc++) {
        float kv = ok ? K[(size_t)(cz * 16 + cc) * NP + p] : 0.f;
        #pragma unroll
        for (int h = 0; h < 8; h++) acc[h] += sqk[h][cc] * kv;
    }
    if (ok) {
        #pragma unroll
        for (int h = 0; h < 8; h++) Ap[(size_t)(cz * 8 + h) * NP + p] = acc[h];
    }
}

// A[h][p] = (sum_cz Ap[cz][h][p] + qb[h]) / sqrt(512)
__global__ __launch_bounds__(256) void k_areduce(const float* __restrict__ Ap,
                                                 const float* __restrict__ qb,
                                                 float* __restrict__ A)
{
    int p = blockIdx.x * 256 + threadIdx.x;
    int h = blockIdx.y;
    if (p >= NP) return;
    float s = 0.f;
    #pragma unroll 8
    for (int cz = 0; cz < 32; cz++) s += Ap[(size_t)(cz * 8 + h) * NP + p];
    const float sc = 0.04419417382415922f;
    A[h * NP + p] = (s + qb[h]) * sc;
}

// ---------------- weight prep (both branches per dispatch) ----------------

__global__ __launch_bounds__(256) void k_cast2(const float* __restrict__ a,
                                               const float* __restrict__ b,
                                               unsigned short* __restrict__ o)
{
    int i = blockIdx.x * 256 + threadIdx.x;   // < 262144
    int br = blockIdx.y;
    const float* src = br ? b : a;
    o[(size_t)br * 262144 + i] = f2bf(src[i]);
}

// (m, c, 3, 3) fp32 -> w2b[br][m][tap*512 + c] bf16
__global__ __launch_bounds__(256) void k_packW2(const float* __restrict__ a,
                                                const float* __restrict__ b,
                                                unsigned short* __restrict__ o)
{
    int i = blockIdx.x * 256 + threadIdx.x;   // over 512*512
    int br = blockIdx.y;
    int m = i >> 9, c = i & 511;
    const float* src = (br ? b : a) + (size_t)i * 9;
    unsigned short* dst = o + (size_t)br * 512 * 4608;
    #pragma unroll
    for (int t = 0; t < 9; t++) dst[(size_t)m * 4608 + t * 512 + c] = f2bf(src[t]);
}

// ---------------- MFMA conv kernels ----------------
// GEMM-T: C[p][m] = sum_k A[p][k] * B[m][k]; 64(p) x 128(m) tile, 4 waves (2x2),
// wave tile 32x64 = 2x4 frags of 16x16, K-chunk 64 (2 mfma k-steps).
// 1D grids with manual decode so bid%8 (XCD, round-robin dispatch) pins data:
//   conv1T: XCD <- bm-range (K-slice + all w1 L2-resident per XCD)
//   conv3T: XCD <- (bn,br) combo (B panel L2-resident; A streamed once per XCD)

// conv1x1: A = K^T (fp32->bf16 LDS transpose), B = w1b[br]. Writes raw bf16 f0b[br].
__global__ __launch_bounds__(256) void k_conv1T(const float* __restrict__ K,
                                                const unsigned short* __restrict__ w1b2,
                                                unsigned short* __restrict__ f0b2)
{
    __shared__ unsigned short As[2][64 * 64];
    __shared__ unsigned short Bs[2][128 * 64];
    int tid = threadIdx.x;
    // decode: XCD u owns bm in [9u, 9u+9) for all 8 (bn,br) combos
    int bid = blockIdx.x;
    int u = bid & 7;
    int t = bid >> 3;                // 0..71
    int bmi = u * 9 + t % 9;
    if (bmi >= 67) return;
    int combo = t / 9;               // 0..7
    int bm = bmi * 64;               // p tile
    int bn = (combo & 3) * 128;      // m tile
    int br = combo >> 2;
    const unsigned short* w1 = w1b2 + (size_t)br * 262144;
    unsigned short* f0 = f0b2 + (size_t)br * NP * 512;
    int lane = tid & 63;
    int w = tid >> 6;
    int wp = (w >> 1) * 32, wm = (w & 1) * 64;
    int rb = tid >> 1, hb = tid & 1;          // B staging map
    int ct = tid >> 4, p4 = (tid & 15) * 4;   // A staging map

    f32x4 acc[2][4];
    #pragma unroll
    for (int i = 0; i < 2; i++)
        #pragma unroll
        for (int j = 0; j < 4; j++) acc[i][j] = (f32x4){0.f, 0.f, 0.f, 0.f};

    float areg[16];
    u32x4 breg[4];

    auto loadRegs = [&](int kc) {
        int c0 = kc * 64;
        #pragma unroll
        for (int pass = 0; pass < 4; pass++) {
            int cl = pass * 16 + ct;
            const float* src = K + (size_t)(c0 + cl) * NP + bm + p4;
            #pragma unroll
            for (int j = 0; j < 4; j++)
                areg[pass * 4 + j] = (bm + p4 + j < NP) ? src[j] : 0.f;
        }
        const unsigned short* brow = w1 + (size_t)(bn + rb) * 512 + c0 + hb * 32;
        #pragma unroll
        for (int j = 0; j < 4; j++) breg[j] = *(const u32x4*)(brow + j * 8);
    };
    auto writeS = [&](int buf) {
        #pragma unroll
        for (int pass = 0; pass < 4; pass++) {
            int cl = pass * 16 + ct;
            #pragma unroll
            for (int j = 0; j < 4; j++) {
                int row = p4 + j;
                int byte = (row * 128 + cl * 2) ^ ((row & 7) << 4);
                *(unsigned short*)((char*)As[buf] + byte) = f2bf(areg[pass * 4 + j]);
            }
        }
        int bb = rb * 128 + hb * 64;
        #pragma unroll
        for (int j = 0; j < 4; j++)
            *(u32x4*)((char*)Bs[buf] + ((bb + j * 16) ^ ((rb & 7) << 4))) = breg[j];
    };

    loadRegs(0);
    writeS(0);
    __syncthreads();
    for (int kc = 0; kc < 8; kc++) {
        if (kc < 7) loadRegs(kc + 1);
        int buf = kc & 1;
        #pragma unroll
        for (int ks = 0; ks < 2; ks++) {
            short8 af[2], bfr[4];
            #pragma unroll
            for (int fi = 0; fi < 2; fi++) {
                int row = wp + fi * 16 + (lane & 15);
                int byte = row * 128 + ((ks * 64 + ((lane >> 4) * 16)) ^ ((row & 7) << 4));
                af[fi] = *(const short8*)((char*)As[buf] + byte);
            }
            #pragma unroll
            for (int fj = 0; fj < 4; fj++) {
                int n = wm + fj * 16 + (lane & 15);
                int byte = n * 128 + ((ks * 64 + ((lane >> 4) * 16)) ^ ((n & 7) << 4));
                bfr[fj] = *(const short8*)((char*)Bs[buf] + byte);
            }
            #pragma unroll
            for (int fi = 0; fi < 2; fi++)
                #pragma unroll
                for (int fj = 0; fj < 4; fj++)
                    acc[fi][fj] = __builtin_amdgcn_mfma_f32_16x16x32_bf16(af[fi], bfr[fj], acc[fi][fj], 0, 0, 0);
        }
        if (kc < 7) writeS((kc + 1) & 1);
        __syncthreads();
    }
    #pragma unroll
    for (int fi = 0; fi < 2; fi++)
        #pragma unroll
        for (int r = 0; r < 4; r++) {
            int p = bm + wp + fi * 16 + (lane >> 4) * 4 + r;
            if (p >= NP) continue;
            #pragma unroll
            for (int fj = 0; fj < 4; fj++) {
                int m = bn + wm + fj * 16 + (lane & 15);
                f0[(size_t)p * 512 + m] = f2bf(acc[fi][fj][r]);
            }
        }
}

// conv3x3 + residual + relu + fused conv8 partial reduction.
// Loop order: kc outer, tap inner (A halo stays L1-resident per kc).
__global__ __launch_bounds__(256) void k_conv3T(const unsigned short* __restrict__ f0b2,
                                                const unsigned short* __restrict__ w2b2,
                                                const float* __restrict__ amp3,
                                                const float* __restrict__ pha3,
                                                float* __restrict__ F2p)
{
    __shared__ unsigned short As[2][64 * 64];
    __shared__ unsigned short Bs[2][128 * 64];
    __shared__ float w3s[8 * 128];
    int tid = threadIdx.x;
    // decode: XCD u owns one (bn,br) combo for all bm (B panel L2-resident)
    int bid = blockIdx.x;
    int u = bid & 7;
    int bmi = bid >> 3;
    if (bmi >= 67) return;
    int bm = bmi * 64;
    int bnq = u & 3;
    int bn = bnq * 128;
    int br = u >> 2;
    const unsigned short* f0 = f0b2 + (size_t)br * NP * 512;
    const unsigned short* w2 = w2b2 + (size_t)br * 512 * 4608;
    const float* w3 = br ? pha3 : amp3;
    for (int i = tid; i < 1024; i += 256) {
        int h = i >> 7, c = i & 127;
        w3s[i] = w3[h * 512 + bn + c];
    }
    int lane = tid & 63;
    int w = tid >> 6;
    int wp = (w >> 1) * 32, wm = (w & 1) * 64;
    int ra = tid >> 2, sa = tid & 3;   // A staging: row, 16-elem segment
    int rb = tid >> 1, hb = tid & 1;   // B staging
    int pA = bm + ra;
    int py = pA / 65, px = pA - py * 65;

    f32x4 acc[2][4];
    #pragma unroll
    for (int i = 0; i < 2; i++)
        #pragma unroll
        for (int j = 0; j < 4; j++) acc[i][j] = (f32x4){0.f, 0.f, 0.f, 0.f};

    u32x4 areg0, areg1, breg[4];

    auto loadRegs = [&](int it) {
        int kc = it / 9, tap = it - kc * 9;    // tap inner: halo L1-resident per kc
        int ky = tap / 3 - 1, kx = tap % 3 - 1;
        int sy = py + ky, sx = px + kx;
        bool valid = (pA < NP) && sy >= 0 && sy < 65 && sx >= 0 && sx < 65;
        int srow = valid ? (pA + ky * 65 + kx) : 0;
        const unsigned short* arow = f0 + (size_t)srow * 512 + kc * 64 + sa * 16;
        u32x4 a0 = relu8(*(const u32x4*)arow);
        u32x4 a1 = relu8(*(const u32x4*)(arow + 8));
        areg0 = valid ? a0 : (u32x4){0, 0, 0, 0};
        areg1 = valid ? a1 : (u32x4){0, 0, 0, 0};
        const unsigned short* brow = w2 + tap * 512 + (size_t)(bn + rb) * 4608 + kc * 64 + hb * 32;
        #pragma unroll
        for (int j = 0; j < 4; j++) breg[j] = *(const u32x4*)(brow + j * 8);
    };
    auto writeS = [&](int buf) {
        int ab = ra * 128 + sa * 32;
        *(u32x4*)((char*)As[buf] + ((ab) ^ ((ra & 7) << 4)))      = areg0;
        *(u32x4*)((char*)As[buf] + ((ab + 16) ^ ((ra & 7) << 4))) = areg1;
        int bb = rb * 128 + hb * 64;
        #pragma unroll
        for (int j = 0; j < 4; j++)
            *(u32x4*)((char*)Bs[buf] + ((bb + j * 16) ^ ((rb & 7) << 4))) = breg[j];
    };

    loadRegs(0);
    writeS(0);
    __syncthreads();
    for (int it = 0; it < 72; it++) {
        if (it < 71) loadRegs(it + 1);
        int buf = it & 1;
        #pragma unroll
        for (int ks = 0; ks < 2; ks++) {
            short8 af[2], bfr[4];
            #pragma unroll
            for (int fi = 0; fi < 2; fi++) {
                int row = wp + fi * 16 + (lane & 15);
                int byte = row * 128 + ((ks * 64 + ((lane >> 4) * 16)) ^ ((row & 7) << 4));
                af[fi] = *(const short8*)((char*)As[buf] + byte);
            }
            #pragma unroll
            for (int fj = 0; fj < 4; fj++) {
                int n = wm + fj * 16 + (lane & 15);
                int byte = n * 128 + ((ks * 64 + ((lane >> 4) * 16)) ^ ((n & 7) << 4));
                bfr[fj] = *(const short8*)((char*)Bs[buf] + byte);
            }
            #pragma unroll
            for (int fi = 0; fi < 2; fi++)
                #pragma unroll
                for (int fj = 0; fj < 4; fj++)
                    acc[fi][fj] = __builtin_amdgcn_mfma_f32_16x16x32_bf16(af[fi], bfr[fj], acc[fi][fj], 0, 0, 0);
        }
        if (it < 71) writeS((it + 1) & 1);
        __syncthreads();
    }
    // epilogue: v = relu(acc + residual) -> LDS (swizzled bf16 tile in Bs[0])
    #pragma unroll
    for (int fi = 0; fi < 2; fi++)
        #pragma unroll
        for (int r = 0; r < 4; r++) {
            int row = wp + fi * 16 + (lane >> 4) * 4 + r;
            int p = bm + row;
            #pragma unroll
            for (int fj = 0; fj < 4; fj++) {
                int mcol = wm + fj * 16 + (lane & 15);
                float v = 0.f;
                if (p < NP)
                    v = fmaxf(acc[fi][fj][r] + bf2f(f0[(size_t)p * 512 + bn + mcol]), 0.f);
                int byte = (row * 256 + mcol * 2) ^ ((row & 7) << 4);
                *(unsigned short*)((char*)Bs[0] + byte) = f2bf(v);
            }
        }
    __syncthreads();
    // fused conv8: partial F2 over this block's 128 channels
    int pl = tid >> 2, qc = tid & 3;
    float a8[8] = {};
    #pragma unroll 4
    for (int jj = 0; jj < 16; jj++) {
        int c = qc * 32 + jj * 2;
        int byte = (pl * 256 + c * 2) ^ ((pl & 7) << 4);
        unsigned int uu = *(const unsigned int*)((char*)Bs[0] + byte);
        float v0 = bf2f((unsigned short)(uu & 0xFFFF));
        float v1 = bf2f((unsigned short)(uu >> 16));
        #pragma unroll
        for (int h = 0; h < 8; h++)
            a8[h] += w3s[h * 128 + c] * v0 + w3s[h * 128 + c + 1] * v1;
    }
    #pragma unroll
    for (int h = 0; h < 8; h++) {
        a8[h] += __shfl_xor(a8[h], 1);
        a8[h] += __shfl_xor(a8[h], 2);
    }
    int p = bm + pl;
    if (qc == 0 && p < NP) {
        float* dst = F2p + (size_t)(br * 4 + bnq) * 8 * NP;
        #pragma unroll
        for (int h = 0; h < 8; h++) dst[h * NP + p] = a8[h];
    }
}

// F2[br][h][p] = relu(sum over 4 bn partials)
__global__ __launch_bounds__(256) void k_f2red(const float* __restrict__ F2p,
                                               float* __restrict__ F2)
{
    int p = blockIdx.x * 256 + threadIdx.x;
    int h = blockIdx.y, br = blockIdx.z;
    if (p >= NP) return;
    float s = 0.f;
    #pragma unroll
    for (int bn = 0; bn < 4; bn++) s += F2p[(size_t)((br * 4 + bn) * 8 + h) * NP + p];
    F2[(size_t)(br * 8 + h) * NP + p] = fmaxf(s, 0.f);
}

// down-proj both branches: Fo[h][j] = sum_p F2[br][h][p] * Wd[j][p] + bd[j]
__global__ __launch_bounds__(256) void k_down(const float* __restrict__ F2,
                                              const float* __restrict__ Wd1,
                                              const float* __restrict__ bd1,
                                              const float* __restrict__ Wd2,
                                              const float* __restrict__ bd2,
                                              float* __restrict__ Fa,
                                              float* __restrict__ Fp)
{
    int wid = threadIdx.x >> 6, lane = threadIdx.x & 63;
    int j = blockIdx.x * 4 + wid;
    if (j >= PR) return;
    int br = blockIdx.y;
    const float* Wd = br ? Wd2 : Wd1;
    const float* bd = br ? bd2 : bd1;
    const float* F2b = F2 + (size_t)br * 8 * NP;
    float* Fo = br ? Fp : Fa;
    const float* wr = Wd + (size_t)j * NP;
    float acc[8] = {};
    for (int p = lane; p < NP; p += 64) {
        float wv = wr[p];
        #pragma unroll
        for (int h = 0; h < 8; h++) acc[h] += wv * F2b[h * NP + p];
    }
    #pragma unroll
    for (int h = 0; h < 8; h++) {
        #pragma unroll
        for (int off = 32; off; off >>= 1) acc[h] += __shfl_down(acc[h], off);
    }
    if (lane == 0) {
        float b = bd[j];
        #pragma unroll
        for (int h = 0; h < 8; h++) Fo[h * PR + j] = acc[h] + b;
    }
}

// ---------------- FFT stages ----------------

__global__ __launch_bounds__(128) void k_twid(double* __restrict__ ctd, double* __restrict__ snd,
                                              float* __restrict__ ctf, float* __restrict__ stf)
{
    int t = threadIdx.x;
    if (t < 65) {
        double ang = 6.283185307179586476925286766559 * (double)t / 65.0;
        double cv = cos(ang), sv = sin(ang);
        ctd[t] = cv; snd[t] = sv;
        ctf[t] = (float)cv; stf[t] = (float)sv;
    }
}

// stage A: T[y][v] = sum_x A[h][y][x] e^{-2pi i v x/65}  (f64 accum)
__global__ __launch_bounds__(64) void k_fftA(const float* __restrict__ A,
                                             const double* __restrict__ ctd,
                                             const double* __restrict__ snd,
                                             float* __restrict__ TrG, float* __restrict__ TiG)
{
    int b = blockIdx.x;
    int h = b / 65, y = b % 65;
    int lane = threadIdx.x;
    __shared__ float rowA[65];
    __shared__ double c65[65], s65[65];
    rowA[lane] = A[h * NP + y * 65 + lane];
    c65[lane] = ctd[lane]; s65[lane] = snd[lane];
    if (lane == 0) {
        rowA[64] = A[h * NP + y * 65 + 64];
        c65[64] = ctd[64]; s65[64] = snd[64];
    }
    __syncthreads();
    int v = lane;
    if (v < 33) {
        double sr = 0.0, si = 0.0;
        for (int x = 0; x < 65; x++) {
            int m = (v * x) % 65;
            double a = (double)rowA[x];
            sr += a * c65[m];
            si -= a * s65[m];
        }
        TrG[(h * 65 + y) * 33 + v] = (float)sr;
        TiG[(h * 65 + y) * 33 + v] = (float)si;
    }
}

// stage B: col-DFT (f64) + amp/phase modulation
__global__ __launch_bounds__(128) void k_fftB(const float* __restrict__ TrG,
                                              const float* __restrict__ TiG,
                                              const float* __restrict__ Fa,
                                              const float* __restrict__ Fp,
                                              const double* __restrict__ ctd,
                                              const double* __restrict__ snd,
                                              float* __restrict__ BrG, float* __restrict__ BiG)
{
    int v = blockIdx.x, h = blockIdx.y;
    int t = threadIdx.x;
    __shared__ float TrS[65], TiS[65];
    __shared__ double c65[65], s65[65];
    if (t < 65) {
        TrS[t] = TrG[(h * 65 + t) * 33 + v];
        TiS[t] = TiG[(h * 65 + t) * 33 + v];
        c65[t] = ctd[t]; s65[t] = snd[t];
    }
    __syncthreads();
    int u = t;
    if (u < 65) {
        double sr = 0.0, si = 0.0;
        for (int y = 0; y < 65; y++) {
            int m = (u * y) % 65;
            double c = c65[m], s = s65[m];
            double tr = (double)TrS[y], ti = (double)TiS[y];
            sr += tr * c + ti * s;
            si += ti * c - tr * s;
        }
        float re = (float)sr, im = (float)si;
        float mag = sqrtf(re * re + im * im);
        float ang = atan2f(im, re);
        int o = u * 33 + v;
        float amp = Fa[h * PR + o] * mag;
        float ph  = Fp[h * PR + o] * ang;
        float sn, cn;
        sincosf(ph, &sn, &cn);
        BrG[(h * 65 + u) * 33 + v] = amp * cn;
        BiG[(h * 65 + u) * 33 + v] = amp * sn;
    }
}

// stage C: inverse col-DFT (f32)
__global__ __launch_bounds__(128) void k_fftC(const float* __restrict__ BrG,
                                              const float* __restrict__ BiG,
                                              const float* __restrict__ ctf,
                                              const float* __restrict__ stf,
                                              float* __restrict__ CrG, float* __restrict__ CiG)
{
    int v = blockIdx.x, h = blockIdx.y;
    int t = threadIdx.x;
    __shared__ float BrS[65], BiS[65];
    __shared__ float c65[65], s65[65];
    if (t < 65) {
        BrS[t] = BrG[(h * 65 + t) * 33 + v];
        BiS[t] = BiG[(h * 65 + t) * 33 + v];
        c65[t] = ctf[t]; s65[t] = stf[t];
    }
    __syncthreads();
    int y = t;
    if (y < 65) {
        float sr = 0.f, si = 0.f;
        for (int u = 0; u < 65; u++) {
            int m = (u * y) % 65;
            float c = c65[m], s = s65[m];
            float ar = BrS[u], ai = BiS[u];
            sr += ar * c - ai * s;
            si += ai * c + ar * s;
        }
        CrG[(h * 65 + y) * 33 + v] = sr;
        CiG[(h * 65 + y) * 33 + v] = si;
    }
}

// stage D: irfft rows
__global__ __launch_bounds__(128) void k_fftD(const float* __restrict__ CrG,
                                              const float* __restrict__ CiG,
                                              const float* __restrict__ ctf,
                                              const float* __restrict__ stf,
                                              float* __restrict__ A2)
{
    int y = blockIdx.x, h = blockIdx.y;
    int t = threadIdx.x;
    __shared__ float CrS[33], CiS[33];
    __shared__ float c65[65], s65[65];
    if (t < 33) {
        CrS[t] = CrG[(h * 65 + y) * 33 + t];
        CiS[t] = CiG[(h * 65 + y) * 33 + t];
    }
    if (t < 65) { c65[t] = ctf[t]; s65[t] = stf[t]; }
    __syncthreads();
    int x = t;
    if (x < 65) {
        float s = CrS[0];
        for (int v = 1; v < 33; v++) {
            int m = (v * x) % 65;
            s += 2.f * (CrS[v] * c65[m] - CiS[v] * s65[m]);
        }
        A2[h * NP + y * 65 + x] = s * (1.f / 4225.f);
    }
}

__global__ __launch_bounds__(1024) void k_softmax(const float* __restrict__ A2,
                                                  float* __restrict__ Wsm)
{
    int h = blockIdx.x, tid = threadIdx.x;
    __shared__ float red[1024];
    float mx = -3.0e38f;
    for (int i = tid; i < NP; i += 1024) mx = fmaxf(mx, A2[h * NP + i]);
    red[tid] = mx; __syncthreads();
    for (int s = 512; s; s >>= 1) {
        if (tid < s) red[tid] = fmaxf(red[tid], red[tid + s]);
        __syncthreads();
    }
    mx = red[0]; __syncthreads();
    float sum = 0.f;
    for (int i = tid; i < NP; i += 1024) sum += expf(A2[h * NP + i] - mx);
    red[tid] = sum; __syncthreads();
    for (int s = 512; s; s >>= 1) {
        if (tid < s) red[tid] += red[tid + s];
        __syncthreads();
    }
    float inv = 1.f / red[0];
    for (int i = tid; i < NP; i += 1024) Wsm[h * NP + i] = expf(A2[h * NP + i] - mx) * inv;
}

__global__ __launch_bounds__(256) void k_t(const float* __restrict__ K,
                                           const float* __restrict__ Wsm,
                                           float* __restrict__ t)
{
    int wid = threadIdx.x >> 6, lane = threadIdx.x & 63;
    int c = blockIdx.x * 4 + wid;
    float acc[8] = {};
    for (int p = lane; p < NP; p += 64) {
        float kv = K[(size_t)c * NP + p];
        #pragma unroll
        for (int h = 0; h < 8; h++) acc[h] += kv * Wsm[h * NP + p];
    }
    #pragma unroll
    for (int h = 0; h < 8; h++) {
        #pragma unroll
        for (int off = 32; off; off >>= 1) acc[h] += __shfl_down(acc[h], off);
    }
    if (lane == 0) {
        #pragma unroll
        for (int h = 0; h < 8; h++) t[h * 512 + c] = acc[h];
    }
}

__global__ __launch_bounds__(256) void k_x(const float* __restrict__ t,
                                           const float* __restrict__ Wv,
                                           const float* __restrict__ bv,
                                           float* __restrict__ x)
{
    int wid = threadIdx.x >> 6, lane = threadIdx.x & 63;
    int hd = blockIdx.x * 4 + wid;
    int h = hd >> 9;
    float s = 0.f;
    for (int c = lane; c < 512; c += 64) s += t[h * 512 + c] * Wv[(size_t)hd * 512 + c];
    #pragma unroll
    for (int off = 32; off; off >>= 1) s += __shfl_down(s, off);
    if (lane == 0) x[hd] = s + bv[hd];
}

__global__ __launch_bounds__(256) void k_out(const float* __restrict__ x,
                                             const float* __restrict__ Wo,
                                             const float* __restrict__ bo,
                                             float* __restrict__ out)
{
    int wid = threadIdx.x >> 6, lane = threadIdx.x & 63;
    int j = blockIdx.x * 4 + wid;
    float s = 0.f;
    for (int i = lane; i < 4096; i += 64) s += x[i] * Wo[(size_t)j * 4096 + i];
    #pragma unroll
    for (int off = 32; off; off >>= 1) s += __shfl_down(s, off);
    if (lane == 0) out[j] = s + bo[j];
}

extern "C" void kernel_launch(void* const* d_in, const int* in_sizes, int n_in,
                              void* d_out, int out_size, void* d_ws, size_t ws_size,
                              hipStream_t stream)
{
    (void)in_sizes; (void)n_in; (void)out_size; (void)ws_size;
    const float* Q    = (const float*)d_in[0];
    const float* K    = (const float*)d_in[1];
    const float* Wq   = (const float*)d_in[2];
    const float* bq   = (const float*)d_in[3];
    const float* Wk   = (const float*)d_in[4];
    const float* bk   = (const float*)d_in[5];
    const float* Wv   = (const float*)d_in[6];
    const float* bv   = (const float*)d_in[7];
    const float* Wo   = (const float*)d_in[8];
    const float* bo   = (const float*)d_in[9];
    const float* amp1 = (const float*)d_in[10];
    const float* amp2 = (const float*)d_in[11];
    const float* amp3 = (const float*)d_in[12];
    const float* pha1 = (const float*)d_in[13];
    const float* pha2 = (const float*)d_in[14];
    const float* pha3 = (const float*)d_in[15];
    const float* Wd1  = (const float*)d_in[16];
    const float* bd1  = (const float*)d_in[17];
    const float* Wd2  = (const float*)d_in[18];
    const float* bd2  = (const float*)d_in[19];
    float* out = (float*)d_out;

    char* w = (char*)d_ws;
    auto alloc = [&](size_t bytes) { char* p = w; w += (bytes + 255) & ~(size_t)255; return p; };
    float* qv   = (float*)alloc(4096 * 4);
    float* qkp  = (float*)alloc(16 * 8 * 512 * 4);
    float* qb   = (float*)alloc(64 * 4);
    float* A    = (float*)alloc(8 * NP * 4);
    unsigned short* w1b2 = (unsigned short*)alloc((size_t)2 * 512 * 512 * 2);
    unsigned short* w2b2 = (unsigned short*)alloc((size_t)2 * 512 * 4608 * 2);
    unsigned short* f0b2 = (unsigned short*)alloc((size_t)2 * NP * 512 * 2);
    float* F2p  = (float*)alloc((size_t)2 * 4 * 8 * NP * 4);
    float* F2   = (float*)alloc((size_t)2 * 8 * NP * 4);
    float* Fa   = (float*)alloc(8 * PR * 4);
    float* Fp   = (float*)alloc(8 * PR * 4);
    double* ctd = (double*)alloc(65 * 8);
    double* snd = (double*)alloc(65 * 8);
    float* ctf  = (float*)alloc(65 * 4);
    float* stf  = (float*)alloc(65 * 4);
    // Ap aliases w2b2 (Ap dead before k_packW2 writes w2b2)
    float* Ap   = (float*)w2b2;
    // post-conv small buffers alias f0b2 (dead after k_conv3T)
    {
        char* s2 = (char*)f0b2;
        auto alias = [&](size_t bytes) { char* p = s2; s2 += (bytes + 255) & ~(size_t)255; return p; };
        float* A2  = (float*)alias(8 * NP * 4);
        float* wsm = (float*)alias(8 * NP * 4);
        float* tt  = (float*)alias(4096 * 4);
        float* xx  = (float*)alias(4096 * 4);
        float* TrG = (float*)alias(8 * PR * 4);
        float* TiG = (float*)alias(8 * PR * 4);
        float* BrG = (float*)alias(8 * PR * 4);
        float* BiG = (float*)alias(8 * PR * 4);
        float* CrG = (float*)alias(8 * PR * 4);
        float* CiG = (float*)alias(8 * PR * 4);

        k_twid<<<1, 128, 0, stream>>>(ctd, snd, ctf, stf);

        // attention logits path (split-K; Ap lives in w2b2 region until areduce)
        k_q<<<1024, 256, 0, stream>>>(Q, Wq, bq, qv);
        k_qk3<<<dim3(2, 8, 16), 256, 0, stream>>>(qv, Wk, qkp);
        k_qb<<<1, 512, 0, stream>>>(qv, bk, qb);
        k_alogits3<<<dim3(17, 32), 256, 0, stream>>>(qkp, K, Ap);
        k_areduce<<<dim3(17, 8), 256, 0, stream>>>(Ap, qb, A);

        // weight prep (overwrites Ap region — after areduce)
        k_cast2<<<dim3(1024, 2), 256, 0, stream>>>(amp1, pha1, w1b2);
        k_packW2<<<dim3(1024, 2), 256, 0, stream>>>(amp2, pha2, w2b2);

        // conv branches, XCD-pinned 1D grids
        k_conv1T<<<576, 256, 0, stream>>>(K, w1b2, f0b2);
        k_conv3T<<<576, 256, 0, stream>>>(f0b2, w2b2, amp3, pha3, F2p);
        k_f2red<<<dim3(17, 8, 2), 256, 0, stream>>>(F2p, F2);
        k_down<<<dim3(537, 2), 256, 0, stream>>>(F2, Wd1, bd1, Wd2, bd2, Fa, Fp);

        // FFT modulation + softmax + output (f0b2 region reused as scratch)
        k_fftA<<<520, 64, 0, stream>>>(A, ctd, snd, TrG, TiG);
        k_fftB<<<dim3(33, 8), 128, 0, stream>>>(TrG, TiG, Fa, Fp, ctd, snd, BrG, BiG);
        k_fftC<<<dim3(33, 8), 128, 0, stream>>>(BrG, BiG, ctf, stf, CrG, CiG);
        k_fftD<<<dim3(65, 8), 128, 0, stream>>>(CrG, CiG, ctf, stf, A2);
        k_softmax<<<8, 1024, 0, stream>>>(A2, wsm);
        k_t<<<128, 256, 0, stream>>>(K, wsm, tt);
        k_x<<<1024, 256, 0, stream>>>(tt, Wv, bv, xx);
        k_out<<<128, 256, 0, stream>>>(xx, Wo, bo, out);
    }
}

// Round 6
// 259.389 us; speedup vs baseline: 6.7083x; 1.0189x over previous
//
#include <hip/hip_runtime.h>
#include <hip/hip_bf16.h>

#define NP 4225      // 65*65 spatial positions
#define PR 2145      // 65*33 rfft bins

typedef __attribute__((ext_vector_type(8))) short short8;    // 8 bf16 (4 VGPRs)
typedef __attribute__((ext_vector_type(4))) float f32x4;
typedef __attribute__((ext_vector_type(4))) unsigned int u32x4;

__device__ inline float bf2f(unsigned short u) {
    union { unsigned int i; float f; } x; x.i = ((unsigned int)u) << 16; return x.f;
}
__device__ inline unsigned short f2bf(float f) {   // RNE
    union { float f; unsigned int i; } x; x.f = f;
    unsigned int r = x.i + 0x7fff + ((x.i >> 16) & 1);
    return (unsigned short)(r >> 16);
}
// relu on 8 packed bf16 (zero halves with sign bit set)
__device__ inline u32x4 relu8(u32x4 v) {
    #pragma unroll
    for (int i = 0; i < 4; i++) {
        unsigned int s = v[i] & 0x80008000u;
        v[i] &= ~((s >> 15) * 0xFFFFu);
    }
    return v;
}

// ---------------- small projection kernels ----------------

__global__ __launch_bounds__(256) void k_q(const float* __restrict__ Q,
                                           const float* __restrict__ Wq,
                                           const float* __restrict__ bq,
                                           float* __restrict__ qv)
{
    int wid = threadIdx.x >> 6, lane = threadIdx.x & 63;
    int j = blockIdx.x * 4 + wid;
    float s = 0.f;
    for (int i = lane; i < 512; i += 64) s += Q[i] * Wq[j * 512 + i];
    #pragma unroll
    for (int off = 32; off; off >>= 1) s += __shfl_down(s, off);
    if (lane == 0) qv[j] = s + bq[j];
}

// qkp[dz][h][c] = sum over 32 d of q[h, dz*32+d] * Wk[h*512+dz*32+d, c]
__global__ __launch_bounds__(256) void k_qk3(const float* __restrict__ qv,
                                             const float* __restrict__ Wk,
                                             float* __restrict__ qkp)
{
    int c = blockIdx.x * 256 + threadIdx.x;
    int h = blockIdx.y, dz = blockIdx.z;
    __shared__ float qs[32];
    if (threadIdx.x < 32) qs[threadIdx.x] = qv[h * 512 + dz * 32 + threadIdx.x];
    __syncthreads();
    float s = 0.f;
    #pragma unroll 8
    for (int d = 0; d < 32; d++)
        s += qs[d] * Wk[(size_t)(h * 512 + dz * 32 + d) * 512 + c];
    qkp[(dz * 8 + h) * 512 + c] = s;
}

__global__ __launch_bounds__(512) void k_qb(const float* __restrict__ q,
                                            const float* __restrict__ bk,
                                            float* __restrict__ qb)
{
    int h = threadIdx.x >> 6, lane = threadIdx.x & 63;
    float s = 0.f;
    for (int d = lane; d < 512; d += 64) s += q[h * 512 + d] * bk[h * 512 + d];
    #pragma unroll
    for (int off = 32; off; off >>= 1) s += __shfl_down(s, off);
    if (lane == 0) qb[h] = s;
}

// Ap[cz][h][p] partials: sum over 16 c of qk[h,c]*K[c,p]
__global__ __launch_bounds__(256) void k_alogits3(const float* __restrict__ qkp,
                                                  const float* __restrict__ K,
                                                  float* __restrict__ Ap)
{
    __shared__ float sqk[8][16];
    int tid = threadIdx.x;
    int cz = blockIdx.y;
    if (tid < 128) {
        int hh = tid >> 4, cc = tid & 15;
        float s = 0.f;
        #pragma unroll
        for (int dz = 0; dz < 16; dz++) s += qkp[(dz * 8 + hh) * 512 + cz * 16 + cc];
        sqk[hh][cc] = s;
    }
    __syncthreads();
    int p = blockIdx.x * 256 + tid;
    bool ok = p < NP;
    float acc[8] = {};
    #pragma unroll
    for (int cc = 0; cc < 16; cc++) {
        float kv = ok ? K[(size_t)(cz * 16 + cc) * NP + p] : 0.f;
        #pragma unroll
        for (int h = 0; h < 8; h++) acc[h] += sqk[h][cc] * kv;
    }
    if (ok) {
        #pragma unroll
        for (int h = 0; h < 8; h++) Ap[(size_t)(cz * 8 + h) * NP + p] = acc[h];
    }
}

// A[h][p] = (sum_cz Ap[cz][h][p] + qb[h]) / sqrt(512)
__global__ __launch_bounds__(256) void k_areduce(const float* __restrict__ Ap,
                                                 const float* __restrict__ qb,
                                                 float* __restrict__ A)
{
    int p = blockIdx.x * 256 + threadIdx.x;
    int h = blockIdx.y;
    if (p >= NP) return;
    float s = 0.f;
    #pragma unroll 8
    for (int cz = 0; cz < 32; cz++) s += Ap[(size_t)(cz * 8 + h) * NP + p];
    const float sc = 0.04419417382415922f;
    A[h * NP + p] = (s + qb[h]) * sc;
}

// ---------------- weight prep (both branches per dispatch) ----------------

__global__ __launch_bounds__(256) void k_cast2(const float* __restrict__ a,
                                               const float* __restrict__ b,
                                               unsigned short* __restrict__ o)
{
    int i = blockIdx.x * 256 + threadIdx.x;   // < 262144
    int br = blockIdx.y;
    const float* src = br ? b : a;
    o[(size_t)br * 262144 + i] = f2bf(src[i]);
}

// (m, c, 3, 3) fp32 -> w2b[br][m][tap*512 + c] bf16
__global__ __launch_bounds__(256) void k_packW2(const float* __restrict__ a,
                                                const float* __restrict__ b,
                                                unsigned short* __restrict__ o)
{
    int i = blockIdx.x * 256 + threadIdx.x;   // over 512*512
    int br = blockIdx.y;
    int m = i >> 9, c = i & 511;
    const float* src = (br ? b : a) + (size_t)i * 9;
    unsigned short* dst = o + (size_t)br * 512 * 4608;
    #pragma unroll
    for (int t = 0; t < 9; t++) dst[(size_t)m * 4608 + t * 512 + c] = f2bf(src[t]);
}

// ---------------- MFMA conv kernels ----------------
// GEMM-T: C[p][m] = sum_k A[p][k] * B[m][k]; 64(p) x 128(m) tile, 4 waves (2x2),
// wave tile 32x64 = 2x4 frags of 16x16, K-chunk 64 (2 mfma k-steps).
// 2-deep register prefetch (two NAMED reg sets) -> compiler emits counted vmcnt;
// load latency hidden across 2 iterations. XCD-pinned 1D grids (bid%8 = XCD).

// conv1x1: A = K^T (fp32->bf16 LDS transpose), B = w1b[br]. Writes raw bf16 f0b[br].
__global__ __launch_bounds__(256) void k_conv1T(const float* __restrict__ K,
                                                const unsigned short* __restrict__ w1b2,
                                                unsigned short* __restrict__ f0b2)
{
    __shared__ unsigned short As[2][64 * 64];
    __shared__ unsigned short Bs[2][128 * 64];
    int tid = threadIdx.x;
    // decode: XCD u owns bm in [9u, 9u+9) for all 8 (bn,br) combos
    int bid = blockIdx.x;
    int u = bid & 7;
    int t = bid >> 3;                // 0..71
    int bmi = u * 9 + t % 9;
    if (bmi >= 67) return;
    int combo = t / 9;               // 0..7
    int bm = bmi * 64;               // p tile
    int bn = (combo & 3) * 128;      // m tile
    int br = combo >> 2;
    const unsigned short* w1 = w1b2 + (size_t)br * 262144;
    unsigned short* f0 = f0b2 + (size_t)br * NP * 512;
    int lane = tid & 63;
    int w = tid >> 6;
    int wp = (w >> 1) * 32, wm = (w & 1) * 64;
    int rb = tid >> 1, hb = tid & 1;          // B staging map
    int ct = tid >> 4, p4 = (tid & 15) * 4;   // A staging map

    f32x4 acc[2][4];
    #pragma unroll
    for (int i = 0; i < 2; i++)
        #pragma unroll
        for (int j = 0; j < 4; j++) acc[i][j] = (f32x4){0.f, 0.f, 0.f, 0.f};

    float aA[16], aB[16];
    u32x4 bA[4], bB[4];

    auto loadRegs = [&](int kc, float (&ar)[16], u32x4 (&brg)[4]) {
        int c0 = kc * 64;
        #pragma unroll
        for (int pass = 0; pass < 4; pass++) {
            int cl = pass * 16 + ct;
            const float* src = K + (size_t)(c0 + cl) * NP + bm + p4;
            #pragma unroll
            for (int j = 0; j < 4; j++)
                ar[pass * 4 + j] = (bm + p4 + j < NP) ? src[j] : 0.f;
        }
        const unsigned short* brow = w1 + (size_t)(bn + rb) * 512 + c0 + hb * 32;
        #pragma unroll
        for (int j = 0; j < 4; j++) brg[j] = *(const u32x4*)(brow + j * 8);
    };
    auto writeS = [&](int buf, float (&ar)[16], u32x4 (&brg)[4]) {
        #pragma unroll
        for (int pass = 0; pass < 4; pass++) {
            int cl = pass * 16 + ct;
            #pragma unroll
            for (int j = 0; j < 4; j++) {
                int row = p4 + j;
                int byte = (row * 128 + cl * 2) ^ ((row & 7) << 4);
                *(unsigned short*)((char*)As[buf] + byte) = f2bf(ar[pass * 4 + j]);
            }
        }
        int bb = rb * 128 + hb * 64;
        #pragma unroll
        for (int j = 0; j < 4; j++)
            *(u32x4*)((char*)Bs[buf] + ((bb + j * 16) ^ ((rb & 7) << 4))) = brg[j];
    };
    auto mfmaStep = [&](int buf) {
        __builtin_amdgcn_s_setprio(1);
        #pragma unroll
        for (int ks = 0; ks < 2; ks++) {
            short8 af[2], bfr[4];
            #pragma unroll
            for (int fi = 0; fi < 2; fi++) {
                int row = wp + fi * 16 + (lane & 15);
                int byte = row * 128 + ((ks * 64 + ((lane >> 4) * 16)) ^ ((row & 7) << 4));
                af[fi] = *(const short8*)((char*)As[buf] + byte);
            }
            #pragma unroll
            for (int fj = 0; fj < 4; fj++) {
                int n = wm + fj * 16 + (lane & 15);
                int byte = n * 128 + ((ks * 64 + ((lane >> 4) * 16)) ^ ((n & 7) << 4));
                bfr[fj] = *(const short8*)((char*)Bs[buf] + byte);
            }
            #pragma unroll
            for (int fi = 0; fi < 2; fi++)
                #pragma unroll
                for (int fj = 0; fj < 4; fj++)
                    acc[fi][fj] = __builtin_amdgcn_mfma_f32_16x16x32_bf16(af[fi], bfr[fj], acc[fi][fj], 0, 0, 0);
        }
        __builtin_amdgcn_s_setprio(0);
    };

    loadRegs(0, aA, bA);
    loadRegs(1, aB, bB);
    writeS(0, aA, bA);
    __syncthreads();
    // 8 kc iterations as 4 unrolled pairs; 2-deep reg prefetch
    for (int ib = 0; ib < 4; ib++) {
        int it = 2 * ib;
        if (it + 2 < 8) loadRegs(it + 2, aA, bA);
        mfmaStep(0);
        writeS(1, aB, bB);
        __syncthreads();
        if (it + 3 < 8) loadRegs(it + 3, aB, bB);
        mfmaStep(1);
        if (it + 2 < 8) writeS(0, aA, bA);
        __syncthreads();
    }
    #pragma unroll
    for (int fi = 0; fi < 2; fi++)
        #pragma unroll
        for (int r = 0; r < 4; r++) {
            int p = bm + wp + fi * 16 + (lane >> 4) * 4 + r;
            if (p >= NP) continue;
            #pragma unroll
            for (int fj = 0; fj < 4; fj++) {
                int m = bn + wm + fj * 16 + (lane & 15);
                f0[(size_t)p * 512 + m] = f2bf(acc[fi][fj][r]);
            }
        }
}

// conv3x3 + residual + relu + fused conv8 partial reduction.
// Loop order: kc outer, tap inner (A halo stays L1/L2-resident per kc).
__global__ __launch_bounds__(256) void k_conv3T(const unsigned short* __restrict__ f0b2,
                                                const unsigned short* __restrict__ w2b2,
                                                const float* __restrict__ amp3,
                                                const float* __restrict__ pha3,
                                                float* __restrict__ F2p)
{
    __shared__ unsigned short As[2][64 * 64];
    __shared__ unsigned short Bs[2][128 * 64];
    __shared__ float w3s[8 * 128];
    int tid = threadIdx.x;
    // decode: XCD u owns one (bn,br) combo for all bm (B panel L2-resident)
    int bid = blockIdx.x;
    int u = bid & 7;
    int bmi = bid >> 3;
    if (bmi >= 67) return;
    int bm = bmi * 64;
    int bnq = u & 3;
    int bn = bnq * 128;
    int br = u >> 2;
    const unsigned short* f0 = f0b2 + (size_t)br * NP * 512;
    const unsigned short* w2 = w2b2 + (size_t)br * 512 * 4608;
    const float* w3 = br ? pha3 : amp3;
    for (int i = tid; i < 1024; i += 256) {
        int h = i >> 7, c = i & 127;
        w3s[i] = w3[h * 512 + bn + c];
    }
    int lane = tid & 63;
    int w = tid >> 6;
    int wp = (w >> 1) * 32, wm = (w & 1) * 64;
    int ra = tid >> 2, sa = tid & 3;   // A staging: row, 16-elem segment
    int rb = tid >> 1, hb = tid & 1;   // B staging
    int pA = bm + ra;
    int py = pA / 65, px = pA - py * 65;

    f32x4 acc[2][4];
    #pragma unroll
    for (int i = 0; i < 2; i++)
        #pragma unroll
        for (int j = 0; j < 4; j++) acc[i][j] = (f32x4){0.f, 0.f, 0.f, 0.f};

    u32x4 aA0, aA1, bA[4];
    u32x4 aB0, aB1, bB[4];

    auto loadRegs = [&](int it, u32x4& a0, u32x4& a1, u32x4 (&brg)[4]) {
        int kc = it / 9, tap = it - kc * 9;    // tap inner: halo cache-resident per kc
        int ky = tap / 3 - 1, kx = tap % 3 - 1;
        int sy = py + ky, sx = px + kx;
        bool valid = (pA < NP) && sy >= 0 && sy < 65 && sx >= 0 && sx < 65;
        int srow = valid ? (pA + ky * 65 + kx) : 0;
        const unsigned short* arow = f0 + (size_t)srow * 512 + kc * 64 + sa * 16;
        u32x4 a0t = relu8(*(const u32x4*)arow);
        u32x4 a1t = relu8(*(const u32x4*)(arow + 8));
        a0 = valid ? a0t : (u32x4){0, 0, 0, 0};
        a1 = valid ? a1t : (u32x4){0, 0, 0, 0};
        const unsigned short* brow = w2 + tap * 512 + (size_t)(bn + rb) * 4608 + kc * 64 + hb * 32;
        #pragma unroll
        for (int j = 0; j < 4; j++) brg[j] = *(const u32x4*)(brow + j * 8);
    };
    auto writeS = [&](int buf, u32x4& a0, u32x4& a1, u32x4 (&brg)[4]) {
        int ab = ra * 128 + sa * 32;
        *(u32x4*)((char*)As[buf] + ((ab) ^ ((ra & 7) << 4)))      = a0;
        *(u32x4*)((char*)As[buf] + ((ab + 16) ^ ((ra & 7) << 4))) = a1;
        int bb = rb * 128 + hb * 64;
        #pragma unroll
        for (int j = 0; j < 4; j++)
            *(u32x4*)((char*)Bs[buf] + ((bb + j * 16) ^ ((rb & 7) << 4))) = brg[j];
    };
    auto mfmaStep = [&](int buf) {
        __builtin_amdgcn_s_setprio(1);
        #pragma unroll
        for (int ks = 0; ks < 2; ks++) {
            short8 af[2], bfr[4];
            #pragma unroll
            for (int fi = 0; fi < 2; fi++) {
                int row = wp + fi * 16 + (lane & 15);
                int byte = row * 128 + ((ks * 64 + ((lane >> 4) * 16)) ^ ((row & 7) << 4));
                af[fi] = *(const short8*)((char*)As[buf] + byte);
            }
            #pragma unroll
            for (int fj = 0; fj < 4; fj++) {
                int n = wm + fj * 16 + (lane & 15);
                int byte = n * 128 + ((ks * 64 + ((lane >> 4) * 16)) ^ ((n & 7) << 4));
                bfr[fj] = *(const short8*)((char*)Bs[buf] + byte);
            }
            #pragma unroll
            for (int fi = 0; fi < 2; fi++)
                #pragma unroll
                for (int fj = 0; fj < 4; fj++)
                    acc[fi][fj] = __builtin_amdgcn_mfma_f32_16x16x32_bf16(af[fi], bfr[fj], acc[fi][fj], 0, 0, 0);
        }
        __builtin_amdgcn_s_setprio(0);
    };

    loadRegs(0, aA0, aA1, bA);
    loadRegs(1, aB0, aB1, bB);
    writeS(0, aA0, aA1, bA);
    __syncthreads();
    // 72 iterations as 36 pairs; 2-deep reg prefetch -> counted vmcnt
    for (int ib = 0; ib < 36; ib++) {
        int it = 2 * ib;
        if (it + 2 < 72) loadRegs(it + 2, aA0, aA1, bA);
        mfmaStep(0);
        writeS(1, aB0, aB1, bB);
        __syncthreads();
        if (it + 3 < 72) loadRegs(it + 3, aB0, aB1, bB);
        mfmaStep(1);
        if (it + 2 < 72) writeS(0, aA0, aA1, bA);
        __syncthreads();
    }
    // epilogue: v = relu(acc + residual) -> LDS (swizzled bf16 tile in Bs[0])
    #pragma unroll
    for (int fi = 0; fi < 2; fi++)
        #pragma unroll
        for (int r = 0; r < 4; r++) {
            int row = wp + fi * 16 + (lane >> 4) * 4 + r;
            int p = bm + row;
            #pragma unroll
            for (int fj = 0; fj < 4; fj++) {
                int mcol = wm + fj * 16 + (lane & 15);
                float v = 0.f;
                if (p < NP)
                    v = fmaxf(acc[fi][fj][r] + bf2f(f0[(size_t)p * 512 + bn + mcol]), 0.f);
                int byte = (row * 256 + mcol * 2) ^ ((row & 7) << 4);
                *(unsigned short*)((char*)Bs[0] + byte) = f2bf(v);
            }
        }
    __syncthreads();
    // fused conv8: partial F2 over this block's 128 channels
    int pl = tid >> 2, qc = tid & 3;
    float a8[8] = {};
    #pragma unroll 4
    for (int jj = 0; jj < 16; jj++) {
        int c = qc * 32 + jj * 2;
        int byte = (pl * 256 + c * 2) ^ ((pl & 7) << 4);
        unsigned int uu = *(const unsigned int*)((char*)Bs[0] + byte);
        float v0 = bf2f((unsigned short)(uu & 0xFFFF));
        float v1 = bf2f((unsigned short)(uu >> 16));
        #pragma unroll
        for (int h = 0; h < 8; h++)
            a8[h] += w3s[h * 128 + c] * v0 + w3s[h * 128 + c + 1] * v1;
    }
    #pragma unroll
    for (int h = 0; h < 8; h++) {
        a8[h] += __shfl_xor(a8[h], 1);
        a8[h] += __shfl_xor(a8[h], 2);
    }
    int p = bm + pl;
    if (qc == 0 && p < NP) {
        float* dst = F2p + (size_t)(br * 4 + bnq) * 8 * NP;
        #pragma unroll
        for (int h = 0; h < 8; h++) dst[h * NP + p] = a8[h];
    }
}

// F2[br][h][p] = relu(sum over 4 bn partials)
__global__ __launch_bounds__(256) void k_f2red(const float* __restrict__ F2p,
                                               float* __restrict__ F2)
{
    int p = blockIdx.x * 256 + threadIdx.x;
    int h = blockIdx.y, br = blockIdx.z;
    if (p >= NP) return;
    float s = 0.f;
    #pragma unroll
    for (int bn = 0; bn < 4; bn++) s += F2p[(size_t)((br * 4 + bn) * 8 + h) * NP + p];
    F2[(size_t)(br * 8 + h) * NP + p] = fmaxf(s, 0.f);
}

// down-proj both branches: Fo[h][j] = sum_p F2[br][h][p] * Wd[j][p] + bd[j]
__global__ __launch_bounds__(256) void k_down(const float* __restrict__ F2,
                                              const float* __restrict__ Wd1,
                                              const float* __restrict__ bd1,
                                              const float* __restrict__ Wd2,
                                              const float* __restrict__ bd2,
                                              float* __restrict__ Fa,
                                              float* __restrict__ Fp)
{
    int wid = threadIdx.x >> 6, lane = threadIdx.x & 63;
    int j = blockIdx.x * 4 + wid;
    if (j >= PR) return;
    int br = blockIdx.y;
    const float* Wd = br ? Wd2 : Wd1;
    const float* bd = br ? bd2 : bd1;
    const float* F2b = F2 + (size_t)br * 8 * NP;
    float* Fo = br ? Fp : Fa;
    const float* wr = Wd + (size_t)j * NP;
    float acc[8] = {};
    for (int p = lane; p < NP; p += 64) {
        float wv = wr[p];
        #pragma unroll
        for (int h = 0; h < 8; h++) acc[h] += wv * F2b[h * NP + p];
    }
    #pragma unroll
    for (int h = 0; h < 8; h++) {
        #pragma unroll
        for (int off = 32; off; off >>= 1) acc[h] += __shfl_down(acc[h], off);
    }
    if (lane == 0) {
        float b = bd[j];
        #pragma unroll
        for (int h = 0; h < 8; h++) Fo[h * PR + j] = acc[h] + b;
    }
}

// ---------------- FFT stages ----------------

__global__ __launch_bounds__(128) void k_twid(double* __restrict__ ctd, double* __restrict__ snd,
                                              float* __restrict__ ctf, float* __restrict__ stf)
{
    int t = threadIdx.x;
    if (t < 65) {
        double ang = 6.283185307179586476925286766559 * (double)t / 65.0;
        double cv = cos(ang), sv = sin(ang);
        ctd[t] = cv; snd[t] = sv;
        ctf[t] = (float)cv; stf[t] = (float)sv;
    }
}

// stage A: T[y][v] = sum_x A[h][y][x] e^{-2pi i v x/65}  (f64 accum)
__global__ __launch_bounds__(64) void k_fftA(const float* __restrict__ A,
                                             const double* __restrict__ ctd,
                                             const double* __restrict__ snd,
                                             float* __restrict__ TrG, float* __restrict__ TiG)
{
    int b = blockIdx.x;
    int h = b / 65, y = b % 65;
    int lane = threadIdx.x;
    __shared__ float rowA[65];
    __shared__ double c65[65], s65[65];
    rowA[lane] = A[h * NP + y * 65 + lane];
    c65[lane] = ctd[lane]; s65[lane] = snd[lane];
    if (lane == 0) {
        rowA[64] = A[h * NP + y * 65 + 64];
        c65[64] = ctd[64]; s65[64] = snd[64];
    }
    __syncthreads();
    int v = lane;
    if (v < 33) {
        double sr = 0.0, si = 0.0;
        for (int x = 0; x < 65; x++) {
            int m = (v * x) % 65;
            double a = (double)rowA[x];
            sr += a * c65[m];
            si -= a * s65[m];
        }
        TrG[(h * 65 + y) * 33 + v] = (float)sr;
        TiG[(h * 65 + y) * 33 + v] = (float)si;
    }
}

// stage B+C fused: col-DFT (f64) + amp/phase modulation (LDS) + inverse col-DFT (f32)
__global__ __launch_bounds__(128) void k_fftBC(const float* __restrict__ TrG,
                                               const float* __restrict__ TiG,
                                               const float* __restrict__ Fa,
                                               const float* __restrict__ Fp,
                                               const double* __restrict__ ctd,
                                               const double* __restrict__ snd,
                                               const float* __restrict__ ctf,
                                               const float* __restrict__ stf,
                                               float* __restrict__ CrG, float* __restrict__ CiG)
{
    int v = blockIdx.x, h = blockIdx.y;
    int t = threadIdx.x;
    __shared__ float TrS[65], TiS[65];
    __shared__ float BrS[65], BiS[65];
    __shared__ double c65[65], s65[65];
    __shared__ float cf[65], sf[65];
    if (t < 65) {
        TrS[t] = TrG[(h * 65 + t) * 33 + v];
        TiS[t] = TiG[(h * 65 + t) * 33 + v];
        c65[t] = ctd[t]; s65[t] = snd[t];
        cf[t] = ctf[t]; sf[t] = stf[t];
    }
    __syncthreads();
    int uu = t;
    if (uu < 65) {
        double sr = 0.0, si = 0.0;
        for (int y = 0; y < 65; y++) {
            int m = (uu * y) % 65;
            double c = c65[m], s = s65[m];
            double tr = (double)TrS[y], ti = (double)TiS[y];
            sr += tr * c + ti * s;
            si += ti * c - tr * s;
        }
        float re = (float)sr, im = (float)si;
        float mag = sqrtf(re * re + im * im);
        float ang = atan2f(im, re);
        int o = uu * 33 + v;
        float amp = Fa[h * PR + o] * mag;
        float ph  = Fp[h * PR + o] * ang;
        float sn, cn;
        sincosf(ph, &sn, &cn);
        BrS[uu] = amp * cn;
        BiS[uu] = amp * sn;
    }
    __syncthreads();
    int y = t;
    if (y < 65) {
        float sr = 0.f, si = 0.f;
        for (int u2 = 0; u2 < 65; u2++) {
            int m = (u2 * y) % 65;
            float c = cf[m], s = sf[m];
            float ar = BrS[u2], ai = BiS[u2];
            sr += ar * c - ai * s;
            si += ai * c + ar * s;
        }
        CrG[(h * 65 + y) * 33 + v] = sr;
        CiG[(h * 65 + y) * 33 + v] = si;
    }
}

// stage D: irfft rows
__global__ __launch_bounds__(128) void k_fftD(const float* __restrict__ CrG,
                                              const float* __restrict__ CiG,
                                              const float* __restrict__ ctf,
                                              const float* __restrict__ stf,
                                              float* __restrict__ A2)
{
    int y = blockIdx.x, h = blockIdx.y;
    int t = threadIdx.x;
    __shared__ float CrS[33], CiS[33];
    __shared__ float c65[65], s65[65];
    if (t < 33) {
        CrS[t] = CrG[(h * 65 + y) * 33 + t];
        CiS[t] = CiG[(h * 65 + y) * 33 + t];
    }
    if (t < 65) { c65[t] = ctf[t]; s65[t] = stf[t]; }
    __syncthreads();
    int x = t;
    if (x < 65) {
        float s = CrS[0];
        for (int v = 1; v < 33; v++) {
            int m = (v * x) % 65;
            s += 2.f * (CrS[v] * c65[m] - CiS[v] * s65[m]);
        }
        A2[h * NP + y * 65 + x] = s * (1.f / 4225.f);
    }
}

__global__ __launch_bounds__(1024) void k_softmax(const float* __restrict__ A2,
                                                  float* __restrict__ Wsm)
{
    int h = blockIdx.x, tid = threadIdx.x;
    __shared__ float red[1024];
    float mx = -3.0e38f;
    for (int i = tid; i < NP; i += 1024) mx = fmaxf(mx, A2[h * NP + i]);
    red[tid] = mx; __syncthreads();
    for (int s = 512; s; s >>= 1) {
        if (tid < s) red[tid] = fmaxf(red[tid], red[tid + s]);
        __syncthreads();
    }
    mx = red[0]; __syncthreads();
    float sum = 0.f;
    for (int i = tid; i < NP; i += 1024) sum += expf(A2[h * NP + i] - mx);
    red[tid] = sum; __syncthreads();
    for (int s = 512; s; s >>= 1) {
        if (tid < s) red[tid] += red[tid + s];
        __syncthreads();
    }
    float inv = 1.f / red[0];
    for (int i = tid; i < NP; i += 1024) Wsm[h * NP + i] = expf(A2[h * NP + i] - mx) * inv;
}

__global__ __launch_bounds__(256) void k_t(const float* __restrict__ K,
                                           const float* __restrict__ Wsm,
                                           float* __restrict__ t)
{
    int wid = threadIdx.x >> 6, lane = threadIdx.x & 63;
    int c = blockIdx.x * 4 + wid;
    float acc[8] = {};
    for (int p = lane; p < NP; p += 64) {
        float kv = K[(size_t)c * NP + p];
        #pragma unroll
        for (int h = 0; h < 8; h++) acc[h] += kv * Wsm[h * NP + p];
    }
    #pragma unroll
    for (int h = 0; h < 8; h++) {
        #pragma unroll
        for (int off = 32; off; off >>= 1) acc[h] += __shfl_down(acc[h], off);
    }
    if (lane == 0) {
        #pragma unroll
        for (int h = 0; h < 8; h++) t[h * 512 + c] = acc[h];
    }
}

__global__ __launch_bounds__(256) void k_x(const float* __restrict__ t,
                                           const float* __restrict__ Wv,
                                           const float* __restrict__ bv,
                                           float* __restrict__ x)
{
    int wid = threadIdx.x >> 6, lane = threadIdx.x & 63;
    int hd = blockIdx.x * 4 + wid;
    int h = hd >> 9;
    float s = 0.f;
    for (int c = lane; c < 512; c += 64) s += t[h * 512 + c] * Wv[(size_t)hd * 512 + c];
    #pragma unroll
    for (int off = 32; off; off >>= 1) s += __shfl_down(s, off);
    if (lane == 0) x[hd] = s + bv[hd];
}

__global__ __launch_bounds__(256) void k_out(const float* __restrict__ x,
                                             const float* __restrict__ Wo,
                                             const float* __restrict__ bo,
                                             float* __restrict__ out)
{
    int wid = threadIdx.x >> 6, lane = threadIdx.x & 63;
    int j = blockIdx.x * 4 + wid;
    float s = 0.f;
    for (int i = lane; i < 4096; i += 64) s += x[i] * Wo[(size_t)j * 4096 + i];
    #pragma unroll
    for (int off = 32; off; off >>= 1) s += __shfl_down(s, off);
    if (lane == 0) out[j] = s + bo[j];
}

extern "C" void kernel_launch(void* const* d_in, const int* in_sizes, int n_in,
                              void* d_out, int out_size, void* d_ws, size_t ws_size,
                              hipStream_t stream)
{
    (void)in_sizes; (void)n_in; (void)out_size; (void)ws_size;
    const float* Q    = (const float*)d_in[0];
    const float* K    = (const float*)d_in[1];
    const float* Wq   = (const float*)d_in[2];
    const float* bq   = (const float*)d_in[3];
    const float* Wk   = (const float*)d_in[4];
    const float* bk   = (const float*)d_in[5];
    const float* Wv   = (const float*)d_in[6];
    const float* bv   = (const float*)d_in[7];
    const float* Wo   = (const float*)d_in[8];
    const float* bo   = (const float*)d_in[9];
    const float* amp1 = (const float*)d_in[10];
    const float* amp2 = (const float*)d_in[11];
    const float* amp3 = (const float*)d_in[12];
    const float* pha1 = (const float*)d_in[13];
    const float* pha2 = (const float*)d_in[14];
    const float* pha3 = (const float*)d_in[15];
    const float* Wd1  = (const float*)d_in[16];
    const float* bd1  = (const float*)d_in[17];
    const float* Wd2  = (const float*)d_in[18];
    const float* bd2  = (const float*)d_in[19];
    float* out = (float*)d_out;

    char* w = (char*)d_ws;
    auto alloc = [&](size_t bytes) { char* p = w; w += (bytes + 255) & ~(size_t)255; return p; };
    float* qv   = (float*)alloc(4096 * 4);
    float* qkp  = (float*)alloc(16 * 8 * 512 * 4);
    float* qb   = (float*)alloc(64 * 4);
    float* A    = (float*)alloc(8 * NP * 4);
    unsigned short* w1b2 = (unsigned short*)alloc((size_t)2 * 512 * 512 * 2);
    unsigned short* w2b2 = (unsigned short*)alloc((size_t)2 * 512 * 4608 * 2);
    unsigned short* f0b2 = (unsigned short*)alloc((size_t)2 * NP * 512 * 2);
    float* F2p  = (float*)alloc((size_t)2 * 4 * 8 * NP * 4);
    float* F2   = (float*)alloc((size_t)2 * 8 * NP * 4);
    float* Fa   = (float*)alloc(8 * PR * 4);
    float* Fp   = (float*)alloc(8 * PR * 4);
    double* ctd = (double*)alloc(65 * 8);
    double* snd = (double*)alloc(65 * 8);
    float* ctf  = (float*)alloc(65 * 4);
    float* stf  = (float*)alloc(65 * 4);
    // Ap aliases w2b2 (Ap dead before k_packW2 writes w2b2)
    float* Ap   = (float*)w2b2;
    // post-conv small buffers alias f0b2 (dead after k_conv3T)
    {
        char* s2 = (char*)f0b2;
        auto alias = [&](size_t bytes) { char* p = s2; s2 += (bytes + 255) & ~(size_t)255; return p; };
        float* A2  = (float*)alias(8 * NP * 4);
        float* wsm = (float*)alias(8 * NP * 4);
        float* tt  = (float*)alias(4096 * 4);
        float* xx  = (float*)alias(4096 * 4);
        float* TrG = (float*)alias(8 * PR * 4);
        float* TiG = (float*)alias(8 * PR * 4);
        float* CrG = (float*)alias(8 * PR * 4);
        float* CiG = (float*)alias(8 * PR * 4);

        k_twid<<<1, 128, 0, stream>>>(ctd, snd, ctf, stf);

        // attention logits path (split-K; Ap lives in w2b2 region until areduce)
        k_q<<<1024, 256, 0, stream>>>(Q, Wq, bq, qv);
        k_qk3<<<dim3(2, 8, 16), 256, 0, stream>>>(qv, Wk, qkp);
        k_qb<<<1, 512, 0, stream>>>(qv, bk, qb);
        k_alogits3<<<dim3(17, 32), 256, 0, stream>>>(qkp, K, Ap);
        k_areduce<<<dim3(17, 8), 256, 0, stream>>>(Ap, qb, A);

        // weight prep (overwrites Ap region — after areduce)
        k_cast2<<<dim3(1024, 2), 256, 0, stream>>>(amp1, pha1, w1b2);
        k_packW2<<<dim3(1024, 2), 256, 0, stream>>>(amp2, pha2, w2b2);

        // conv branches, XCD-pinned 1D grids, 2-deep pipelined
        k_conv1T<<<576, 256, 0, stream>>>(K, w1b2, f0b2);
        k_conv3T<<<576, 256, 0, stream>>>(f0b2, w2b2, amp3, pha3, F2p);
        k_f2red<<<dim3(17, 8, 2), 256, 0, stream>>>(F2p, F2);
        k_down<<<dim3(537, 2), 256, 0, stream>>>(F2, Wd1, bd1, Wd2, bd2, Fa, Fp);

        // FFT modulation + softmax + output (f0b2 region reused as scratch)
        k_fftA<<<520, 64, 0, stream>>>(A, ctd, snd, TrG, TiG);
        k_fftBC<<<dim3(33, 8), 128, 0, stream>>>(TrG, TiG, Fa, Fp, ctd, snd, ctf, stf, CrG, CiG);
        k_fftD<<<dim3(65, 8), 128, 0, stream>>>(CrG, CiG, ctf, stf, A2);
        k_softmax<<<8, 1024, 0, stream>>>(A2, wsm);
        k_t<<<128, 256, 0, stream>>>(K, wsm, tt);
        k_x<<<1024, 256, 0, stream>>>(tt, Wv, bv, xx);
        k_out<<<128, 256, 0, stream>>>(xx, Wo, bo, out);
    }
}